// Round 1
// baseline (773.827 us; speedup 1.0000x reference)
//
#include <hip/hip_runtime.h>
#include <hip/hip_bf16.h>

#define NB 4
#define TT 2048
#define CC 2048
#define HH 16
#define DD 128

typedef short bvec8 __attribute__((ext_vector_type(8)));
typedef float fvec4 __attribute__((ext_vector_type(4)));

__device__ __forceinline__ void gload16(const void* g, void* l) {
  __builtin_amdgcn_global_load_lds(
      (__attribute__((address_space(1))) void*)g,
      (__attribute__((address_space(3))) void*)l, 16, 0, 0);
}

__device__ __forceinline__ unsigned short f2bf(float f) {
  union { float f; unsigned int u; } x; x.f = f;
  unsigned int u = x.u;
  return (unsigned short)((u + 0x7FFFu + ((u >> 16) & 1u)) >> 16);
}

__device__ __forceinline__ fvec4 mfma16(bvec8 a, bvec8 b, fvec4 c) {
  return __builtin_amdgcn_mfma_f32_16x16x32_bf16(a, b, c, 0, 0, 0);
}

// ---------------- convert fp32 -> bf16 (vectorized) ----------------
__global__ __launch_bounds__(256) void k_cvt(const float* __restrict__ in,
                                             unsigned short* __restrict__ out, int n4) {
  int i = blockIdx.x * 256 + threadIdx.x;
  if (i >= n4) return;
  float4 v = ((const float4*)in)[i];
  ushort4 o;
  o.x = f2bf(v.x); o.y = f2bf(v.y); o.z = f2bf(v.z); o.w = f2bf(v.w);
  ((ushort4*)out)[i] = o;
}

// ---------------- transpose fp32 [R][Cn] -> bf16 [Cn][R] ----------------
__global__ __launch_bounds__(256) void k_transpose(const float* __restrict__ in,
                                                   unsigned short* __restrict__ out,
                                                   int R, int Cn) {
  __shared__ unsigned short tile[64][65];
  int tC = blockIdx.x * 64, tR = blockIdx.y * 64;
  int t = threadIdx.x;
  for (int i = 0; i < 16; i++) {
    int idx = t + i * 256; int r = idx >> 6, c = idx & 63;
    tile[r][c] = f2bf(in[(size_t)(tR + r) * Cn + tC + c]);
  }
  __syncthreads();
  for (int i = 0; i < 16; i++) {
    int idx = t + i * 256; int r = idx >> 6, c = idx & 63;
    out[(size_t)(tC + r) * R + tR + c] = tile[c][r];
  }
}

// ---------------- QKV GEMM: [8192,2048]x[2048,6144]+bias -> q,k [2][B][H][T][D], v^T [B][H][D][T]
__global__ __launch_bounds__(256) void k_gemm_qkv(
    const unsigned short* __restrict__ A,    // xb [8192][2048] bf16
    const unsigned short* __restrict__ Bt,   // w_attn^T [6144][2048] bf16
    const float* __restrict__ bias,          // [6144]
    unsigned short* __restrict__ qk,         // [2][B][H][T][D]
    unsigned short* __restrict__ vt) {       // [B][H][D][T]
  const int K = CC;
  __shared__ unsigned short As[128 * 32];
  __shared__ unsigned short Bs[128 * 32];
  int tid = threadIdx.x, wid = tid >> 6, ln = tid & 63;
  int gl = ln >> 4, lo = ln & 15;
  int m0 = blockIdx.y * 128, n0 = blockIdx.x * 128;
  int wr = wid >> 1, wc = wid & 1;
  fvec4 acc[4][4];
  fvec4 zero = {0.f, 0.f, 0.f, 0.f};
#pragma unroll
  for (int i = 0; i < 4; i++)
#pragma unroll
    for (int j = 0; j < 4; j++) acc[i][j] = zero;

  for (int k0 = 0; k0 < K; k0 += 32) {
#pragma unroll
    for (int j = 0; j < 2; j++) {
      int chunk = j * 256 + tid;
      int row = chunk >> 2, kc = chunk & 3;
      gload16(A + (size_t)(m0 + row) * K + k0 + kc * 8, &As[(j * 256 + wid * 64) * 8]);
    }
#pragma unroll
    for (int j = 0; j < 2; j++) {
      int chunk = j * 256 + tid;
      int row = chunk >> 2, kc = chunk & 3;
      gload16(Bt + (size_t)(n0 + row) * K + k0 + kc * 8, &Bs[(j * 256 + wid * 64) * 8]);
    }
    __syncthreads();
    bvec8 af[4], bf[4];
#pragma unroll
    for (int f = 0; f < 4; f++)
      af[f] = *(const bvec8*)&As[(wr * 64 + f * 16 + lo) * 32 + gl * 8];
#pragma unroll
    for (int f = 0; f < 4; f++)
      bf[f] = *(const bvec8*)&Bs[(wc * 64 + f * 16 + lo) * 32 + gl * 8];
#pragma unroll
    for (int i = 0; i < 4; i++)
#pragma unroll
      for (int j = 0; j < 4; j++) acc[i][j] = mfma16(af[i], bf[j], acc[i][j]);
    __syncthreads();
  }

#pragma unroll
  for (int fn = 0; fn < 4; fn++) {
    int n = n0 + wc * 64 + fn * 16 + lo;
    float bn = bias[n];
    int s = n >> 11, hh = (n >> 7) & 15, d = n & 127;
#pragma unroll
    for (int fm = 0; fm < 4; fm++) {
      int mb = m0 + wr * 64 + fm * 16 + gl * 4;
      int b = mb >> 11, t0 = mb & 2047;
      if (s < 2) {
        size_t base = ((((size_t)s * NB + b) * HH + hh) * TT) * DD;
#pragma unroll
        for (int r = 0; r < 4; r++)
          qk[base + (size_t)(t0 + r) * DD + d] = f2bf(acc[fm][fn][r] + bn);
      } else {
        size_t base = (((size_t)b * HH + hh) * DD + d) * TT + t0;
        ushort4 o;
        o.x = f2bf(acc[fm][fn][0] + bn);
        o.y = f2bf(acc[fm][fn][1] + bn);
        o.z = f2bf(acc[fm][fn][2] + bn);
        o.w = f2bf(acc[fm][fn][3] + bn);
        *(ushort4*)&vt[base] = o;
      }
    }
  }
}

// ---------------- flash attention (causal), 64 q-rows/block, KV tile 64 ----------------
__global__ __launch_bounds__(256) void k_attn(
    const unsigned short* __restrict__ qk,   // [2][B][H][T][D]
    const unsigned short* __restrict__ vt,   // [B][H][D][T]
    unsigned short* __restrict__ yb) {       // [B][T][C]
  __shared__ unsigned short Ks[64 * 128];    // [kk][d], chunk-swizzled
  __shared__ unsigned short Vs[128 * 64];    // [d][kk], chunk-swizzled
  __shared__ unsigned short Ps[4][16 * 64];  // per-wave P, chunk-swizzled
  int tid = threadIdx.x, wid = tid >> 6, ln = tid & 63;
  int gl = ln >> 4, lo = ln & 15;
  int qt = blockIdx.x & 31;
  int bh = blockIdx.x >> 5;
  int b = bh >> 4, h = bh & 15;
  const unsigned short* Q  = qk + (((size_t)b * HH + h) * TT) * DD;
  const unsigned short* Kg = qk + ((((size_t)NB + b) * HH + h) * TT) * DD;
  const unsigned short* Vg = vt + (((size_t)b * HH + h) * DD) * TT;
  int q0w = qt * 64 + wid * 16;

  bvec8 qf[4];
#pragma unroll
  for (int ks = 0; ks < 4; ks++)
    qf[ks] = *(const bvec8*)(Q + (size_t)(q0w + lo) * DD + ks * 32 + gl * 8);

  fvec4 oacc[8];
  fvec4 zero = {0.f, 0.f, 0.f, 0.f};
#pragma unroll
  for (int i = 0; i < 8; i++) oacc[i] = zero;
  float mrun[4] = {-1e30f, -1e30f, -1e30f, -1e30f};
  float lrun[4] = {0.f, 0.f, 0.f, 0.f};
  const float sc = 0.08838834764831845f * 1.4426950408889634f;  // scale * log2(e)

  int ntiles = qt + 1;
  for (int it = 0; it < ntiles; it++) {
    int k0 = it * 64;
    // stage K tile [64][128] (16 chunks/row) and V^T tile [128][64] (8 chunks/row)
#pragma unroll
    for (int j = 0; j < 4; j++) {
      int c = j * 256 + tid;
      int r = c >> 4, cc = c & 15;
      gload16(Kg + (size_t)(k0 + r) * DD + ((cc ^ (r & 7)) * 8), &Ks[(j * 256 + wid * 64) * 8]);
    }
#pragma unroll
    for (int j = 0; j < 4; j++) {
      int c = j * 256 + tid;
      int r = c >> 3, cc = c & 7;
      gload16(Vg + (size_t)r * TT + k0 + ((cc ^ (r & 7)) * 8), &Vs[(j * 256 + wid * 64) * 8]);
    }
    __syncthreads();

    // S = Q K^T  (16 MFMAs)
    fvec4 sa[4];
#pragma unroll
    for (int fn = 0; fn < 4; fn++) {
      fvec4 s = zero;
#pragma unroll
      for (int ks = 0; ks < 4; ks++) {
        int r = fn * 16 + lo;
        int cd = ks * 4 + gl;
        bvec8 kf = *(const bvec8*)&Ks[(r * 16 + (cd ^ (r & 7))) * 8];
        s = mfma16(qf[ks], kf, s);
      }
      sa[fn] = s;
    }

    // online softmax (per q-row; row r lives at lanes sharing gl, cols across lo+fn)
    float p[4][4];
#pragma unroll
    for (int r = 0; r < 4; r++) {
      int qrow = q0w + gl * 4 + r;
      float mx = -1e30f;
#pragma unroll
      for (int fn = 0; fn < 4; fn++) {
        int kkg = k0 + fn * 16 + lo;
        float v = (kkg <= qrow) ? sa[fn][r] * sc : -1e30f;
        p[fn][r] = v;
        mx = fmaxf(mx, v);
      }
#pragma unroll
      for (int dlt = 1; dlt < 16; dlt <<= 1) mx = fmaxf(mx, __shfl_xor(mx, dlt));
      float mnew = fmaxf(mrun[r], mx);
      float corr = exp2f(mrun[r] - mnew);
      mrun[r] = mnew;
      float ls = 0.f;
#pragma unroll
      for (int fn = 0; fn < 4; fn++) {
        float pv = exp2f(p[fn][r] - mnew);
        p[fn][r] = pv;
        ls += pv;
      }
#pragma unroll
      for (int dlt = 1; dlt < 16; dlt <<= 1) ls += __shfl_xor(ls, dlt);
      lrun[r] = lrun[r] * corr + ls;
#pragma unroll
      for (int fd = 0; fd < 8; fd++) oacc[fd][r] *= corr;
    }

    // write P (bf16) to per-wave LDS, swizzled
#pragma unroll
    for (int fn = 0; fn < 4; fn++)
#pragma unroll
      for (int r = 0; r < 4; r++) {
        int qr = gl * 4 + r;
        int kc = fn * 16 + lo;
        Ps[wid][(qr * 8 + (((kc >> 3) ^ (qr & 7)))) * 8 + (kc & 7)] = f2bf(p[fn][r]);
      }

    // O += P V  (16 MFMAs)
#pragma unroll
    for (int ks2 = 0; ks2 < 2; ks2++) {
      bvec8 pf = *(const bvec8*)&Ps[wid][(lo * 8 + ((ks2 * 4 + gl) ^ (lo & 7))) * 8];
#pragma unroll
      for (int fd = 0; fd < 8; fd++) {
        int rd = fd * 16 + lo;
        int ck = ks2 * 4 + gl;
        bvec8 vf = *(const bvec8*)&Vs[(rd * 8 + (ck ^ (rd & 7))) * 8];
        oacc[fd] = mfma16(pf, vf, oacc[fd]);
      }
    }
    __syncthreads();
  }

  // epilogue: O / l -> yb [B][T][C]
#pragma unroll
  for (int r = 0; r < 4; r++) {
    int qrow = q0w + gl * 4 + r;
    float inv = 1.f / lrun[r];
#pragma unroll
    for (int fd = 0; fd < 8; fd++) {
      int d = fd * 16 + lo;
      yb[((size_t)b * TT + qrow) * CC + h * DD + d] = f2bf(oacc[fd][r] * inv);
    }
  }
}

// ---------------- proj GEMM: [8192,2048]x[2048,2048]+bias -> fp32 out ----------------
__global__ __launch_bounds__(256) void k_gemm_proj(
    const unsigned short* __restrict__ A,    // yb [8192][2048]
    const unsigned short* __restrict__ Bt,   // w_proj^T [2048][2048]
    const float* __restrict__ bias,          // [2048]
    float* __restrict__ out) {               // [8192][2048]
  const int K = CC;
  __shared__ unsigned short As[128 * 32];
  __shared__ unsigned short Bs[128 * 32];
  int tid = threadIdx.x, wid = tid >> 6, ln = tid & 63;
  int gl = ln >> 4, lo = ln & 15;
  int m0 = blockIdx.y * 128, n0 = blockIdx.x * 128;
  int wr = wid >> 1, wc = wid & 1;
  fvec4 acc[4][4];
  fvec4 zero = {0.f, 0.f, 0.f, 0.f};
#pragma unroll
  for (int i = 0; i < 4; i++)
#pragma unroll
    for (int j = 0; j < 4; j++) acc[i][j] = zero;

  for (int k0 = 0; k0 < K; k0 += 32) {
#pragma unroll
    for (int j = 0; j < 2; j++) {
      int chunk = j * 256 + tid;
      int row = chunk >> 2, kc = chunk & 3;
      gload16(A + (size_t)(m0 + row) * K + k0 + kc * 8, &As[(j * 256 + wid * 64) * 8]);
    }
#pragma unroll
    for (int j = 0; j < 2; j++) {
      int chunk = j * 256 + tid;
      int row = chunk >> 2, kc = chunk & 3;
      gload16(Bt + (size_t)(n0 + row) * K + k0 + kc * 8, &Bs[(j * 256 + wid * 64) * 8]);
    }
    __syncthreads();
    bvec8 af[4], bf[4];
#pragma unroll
    for (int f = 0; f < 4; f++)
      af[f] = *(const bvec8*)&As[(wr * 64 + f * 16 + lo) * 32 + gl * 8];
#pragma unroll
    for (int f = 0; f < 4; f++)
      bf[f] = *(const bvec8*)&Bs[(wc * 64 + f * 16 + lo) * 32 + gl * 8];
#pragma unroll
    for (int i = 0; i < 4; i++)
#pragma unroll
      for (int j = 0; j < 4; j++) acc[i][j] = mfma16(af[i], bf[j], acc[i][j]);
    __syncthreads();
  }

#pragma unroll
  for (int fn = 0; fn < 4; fn++) {
    int n = n0 + wc * 64 + fn * 16 + lo;
    float bn = bias[n];
#pragma unroll
    for (int fm = 0; fm < 4; fm++) {
      int m = m0 + wr * 64 + fm * 16 + gl * 4;
#pragma unroll
      for (int r = 0; r < 4; r++) out[(size_t)(m + r) * CC + n] = acc[fm][fn][r] + bn;
    }
  }
}

extern "C" void kernel_launch(void* const* d_in, const int* in_sizes, int n_in,
                              void* d_out, int out_size, void* d_ws, size_t ws_size,
                              hipStream_t stream) {
  const float* x      = (const float*)d_in[0];
  const float* w_attn = (const float*)d_in[1];
  const float* b_attn = (const float*)d_in[2];
  const float* w_proj = (const float*)d_in[3];
  const float* b_proj = (const float*)d_in[4];
  float* out = (float*)d_out;

  char* ws = (char*)d_ws;
  unsigned short* xb    = (unsigned short*)(ws);                         // 32 MB
  unsigned short* wab_t = (unsigned short*)(ws + 33554432);              // 24 MB
  unsigned short* wpb_t = (unsigned short*)(ws + 58720256);              // 8 MB
  unsigned short* qkws  = (unsigned short*)(ws + 67108864);              // 64 MB
  unsigned short* vtws  = (unsigned short*)(ws + 134217728);             // 32 MB
  unsigned short* ybws  = (unsigned short*)(ws + 167772160);             // 32 MB

  hipLaunchKernelGGL(k_cvt, dim3(16384), dim3(256), 0, stream, x, xb, 4194304);
  hipLaunchKernelGGL(k_transpose, dim3(96, 32), dim3(256), 0, stream, w_attn, wab_t, 2048, 6144);
  hipLaunchKernelGGL(k_transpose, dim3(32, 32), dim3(256), 0, stream, w_proj, wpb_t, 2048, 2048);
  hipLaunchKernelGGL(k_gemm_qkv, dim3(48, 64), dim3(256), 0, stream, xb, wab_t, b_attn, qkws, vtws);
  hipLaunchKernelGGL(k_attn, dim3(2048), dim3(256), 0, stream, qkws, vtws, ybws);
  hipLaunchKernelGGL(k_gemm_proj, dim3(16, 64), dim3(256), 0, stream, ybws, wpb_t, b_proj, out);
}

// Round 2
// 620.103 us; speedup vs baseline: 1.2479x; 1.2479x over previous
//
#include <hip/hip_runtime.h>
#include <hip/hip_bf16.h>

#define NB 4
#define TT 2048
#define CC 2048
#define HH 16
#define DD 128

typedef short bvec8 __attribute__((ext_vector_type(8)));
typedef float fvec4 __attribute__((ext_vector_type(4)));

__device__ __forceinline__ void gload16(const void* g, void* l) {
  __builtin_amdgcn_global_load_lds(
      (__attribute__((address_space(1))) void*)g,
      (__attribute__((address_space(3))) void*)l, 16, 0, 0);
}

__device__ __forceinline__ unsigned short f2bf(float f) {
  union { float f; unsigned int u; } x; x.f = f;
  unsigned int u = x.u;
  return (unsigned short)((u + 0x7FFFu + ((u >> 16) & 1u)) >> 16);
}

__device__ __forceinline__ fvec4 mfma16(bvec8 a, bvec8 b, fvec4 c) {
  return __builtin_amdgcn_mfma_f32_16x16x32_bf16(a, b, c, 0, 0, 0);
}

// scale * log2(e), folded into K at the QKV epilogue
#define KSC (0.08838834764831845f * 1.4426950408889634f)

// ---------------- convert fp32 -> bf16 (vectorized) ----------------
__global__ __launch_bounds__(256) void k_cvt(const float* __restrict__ in,
                                             unsigned short* __restrict__ out, int n4) {
  int i = blockIdx.x * 256 + threadIdx.x;
  if (i >= n4) return;
  float4 v = ((const float4*)in)[i];
  ushort4 o;
  o.x = f2bf(v.x); o.y = f2bf(v.y); o.z = f2bf(v.z); o.w = f2bf(v.w);
  ((ushort4*)out)[i] = o;
}

// ---------------- transpose fp32 [R][Cn] -> bf16 [Cn][R] ----------------
__global__ __launch_bounds__(256) void k_transpose(const float* __restrict__ in,
                                                   unsigned short* __restrict__ out,
                                                   int R, int Cn) {
  __shared__ unsigned short tile[64][65];
  int tC = blockIdx.x * 64, tR = blockIdx.y * 64;
  int t = threadIdx.x;
  for (int i = 0; i < 16; i++) {
    int idx = t + i * 256; int r = idx >> 6, c = idx & 63;
    tile[r][c] = f2bf(in[(size_t)(tR + r) * Cn + tC + c]);
  }
  __syncthreads();
  for (int i = 0; i < 16; i++) {
    int idx = t + i * 256; int r = idx >> 6, c = idx & 63;
    out[(size_t)(tC + r) * R + tR + c] = tile[c][r];
  }
}

// ---------------- QKV GEMM: [8192,2048]x[2048,6144]+bias -> q,k [2][B][H][T][D], v^T [B][H][D][T]
__global__ __launch_bounds__(256) void k_gemm_qkv(
    const unsigned short* __restrict__ A,    // xb [8192][2048] bf16
    const unsigned short* __restrict__ Bt,   // w_attn^T [6144][2048] bf16
    const float* __restrict__ bias,          // [6144]
    unsigned short* __restrict__ qk,         // [2][B][H][T][D]
    unsigned short* __restrict__ vt) {       // [B][H][D][T]
  const int K = CC;
  __shared__ unsigned short As[128 * 32];
  __shared__ unsigned short Bs[128 * 32];
  int tid = threadIdx.x, wid = tid >> 6, ln = tid & 63;
  int gl = ln >> 4, lo = ln & 15;
  // XCD-aware bijective swizzle (grid = 48*64 = 3072, %8==0)
  unsigned nx = gridDim.x;
  unsigned orig = blockIdx.y * nx + blockIdx.x;
  unsigned cpx = (nx * gridDim.y) >> 3;
  unsigned wg = (orig & 7) * cpx + (orig >> 3);
  int m0 = (int)(wg / nx) * 128, n0 = (int)(wg % nx) * 128;
  int wr = wid >> 1, wc = wid & 1;
  fvec4 acc[4][4];
  fvec4 zero = {0.f, 0.f, 0.f, 0.f};
#pragma unroll
  for (int i = 0; i < 4; i++)
#pragma unroll
    for (int j = 0; j < 4; j++) acc[i][j] = zero;

  for (int k0 = 0; k0 < K; k0 += 32) {
#pragma unroll
    for (int j = 0; j < 2; j++) {
      int chunk = j * 256 + tid;
      int row = chunk >> 2, kc = chunk & 3;
      gload16(A + (size_t)(m0 + row) * K + k0 + kc * 8, &As[(j * 256 + wid * 64) * 8]);
    }
#pragma unroll
    for (int j = 0; j < 2; j++) {
      int chunk = j * 256 + tid;
      int row = chunk >> 2, kc = chunk & 3;
      gload16(Bt + (size_t)(n0 + row) * K + k0 + kc * 8, &Bs[(j * 256 + wid * 64) * 8]);
    }
    __syncthreads();
    bvec8 af[4], bf[4];
#pragma unroll
    for (int f = 0; f < 4; f++)
      af[f] = *(const bvec8*)&As[(wr * 64 + f * 16 + lo) * 32 + gl * 8];
#pragma unroll
    for (int f = 0; f < 4; f++)
      bf[f] = *(const bvec8*)&Bs[(wc * 64 + f * 16 + lo) * 32 + gl * 8];
#pragma unroll
    for (int i = 0; i < 4; i++)
#pragma unroll
      for (int j = 0; j < 4; j++) acc[i][j] = mfma16(af[i], bf[j], acc[i][j]);
    __syncthreads();
  }

#pragma unroll
  for (int fn = 0; fn < 4; fn++) {
    int n = n0 + wc * 64 + fn * 16 + lo;
    float bn = bias[n];
    int s = n >> 11, hh = (n >> 7) & 15, d = n & 127;
    float mulv = (s == 1) ? KSC : 1.0f;   // pre-scale K by scale*log2e
#pragma unroll
    for (int fm = 0; fm < 4; fm++) {
      int mb = m0 + wr * 64 + fm * 16 + gl * 4;
      int b = mb >> 11, t0 = mb & 2047;
      if (s < 2) {
        size_t base = ((((size_t)s * NB + b) * HH + hh) * TT) * DD;
#pragma unroll
        for (int r = 0; r < 4; r++)
          qk[base + (size_t)(t0 + r) * DD + d] = f2bf((acc[fm][fn][r] + bn) * mulv);
      } else {
        size_t base = (((size_t)b * HH + hh) * DD + d) * TT + t0;
        ushort4 o;
        o.x = f2bf(acc[fm][fn][0] + bn);
        o.y = f2bf(acc[fm][fn][1] + bn);
        o.z = f2bf(acc[fm][fn][2] + bn);
        o.w = f2bf(acc[fm][fn][3] + bn);
        *(ushort4*)&vt[base] = o;
      }
    }
  }
}

// ---------------- flash attention (causal), paired q-tiles (qt, 31-qt) per block ----------------
__global__ __launch_bounds__(256) void k_attn(
    const unsigned short* __restrict__ qk,   // [2][B][H][T][D], K pre-scaled
    const unsigned short* __restrict__ vt,   // [B][H][D][T]
    unsigned short* __restrict__ yb) {       // [B][T][C]
  __shared__ unsigned short Ks[64 * 128];    // [kk][d], chunk-swizzled
  __shared__ unsigned short Vs[128 * 64];    // [d][kk], chunk-swizzled
  __shared__ unsigned short Ps[4][16 * 64];  // per-wave P, chunk-swizzled
  int tid = threadIdx.x, wid = tid >> 6, ln = tid & 63;
  int gl = ln >> 4, lo = ln & 15;
  int qp = blockIdx.x & 15;                  // pair index 0..15
  int bh = blockIdx.x >> 4;
  int b = bh >> 4, h = bh & 15;
  const unsigned short* Q  = qk + (((size_t)b * HH + h) * TT) * DD;
  const unsigned short* Kg = qk + ((((size_t)NB + b) * HH + h) * TT) * DD;
  const unsigned short* Vg = vt + (((size_t)b * HH + h) * DD) * TT;
  fvec4 zero = {0.f, 0.f, 0.f, 0.f};

  for (int pass = 0; pass < 2; pass++) {
    int qt = pass ? (31 - qp) : qp;          // combined work = 33 tiles, all blocks equal
    int q0w = qt * 64 + wid * 16;

    bvec8 qf[4];
#pragma unroll
    for (int ks = 0; ks < 4; ks++)
      qf[ks] = *(const bvec8*)(Q + (size_t)(q0w + lo) * DD + ks * 32 + gl * 8);

    fvec4 oacc[8];
#pragma unroll
    for (int i = 0; i < 8; i++) oacc[i] = zero;
    float mrun[4] = {-1e30f, -1e30f, -1e30f, -1e30f};
    float lrun[4] = {0.f, 0.f, 0.f, 0.f};

    int ntiles = qt + 1;
    for (int it = 0; it < ntiles; it++) {
      int k0 = it * 64;
      // stage K tile [64][128] and V^T tile [128][64], chunk-XOR swizzled
#pragma unroll
      for (int j = 0; j < 4; j++) {
        int c = j * 256 + tid;
        int r = c >> 4, cc = c & 15;
        gload16(Kg + (size_t)(k0 + r) * DD + ((cc ^ (r & 7)) * 8), &Ks[(j * 256 + wid * 64) * 8]);
      }
#pragma unroll
      for (int j = 0; j < 4; j++) {
        int c = j * 256 + tid;
        int r = c >> 3, cc = c & 7;
        gload16(Vg + (size_t)r * TT + k0 + ((cc ^ (r & 7)) * 8), &Vs[(j * 256 + wid * 64) * 8]);
      }
      __syncthreads();

      // S = Q K^T  (16 MFMAs); K is pre-scaled so S is already in log2 units
      fvec4 sa[4];
#pragma unroll
      for (int fn = 0; fn < 4; fn++) {
        fvec4 s = zero;
#pragma unroll
        for (int ks = 0; ks < 4; ks++) {
          int r = fn * 16 + lo;
          int cd = ks * 4 + gl;
          bvec8 kf = *(const bvec8*)&Ks[(r * 16 + (cd ^ (r & 7))) * 8];
          s = mfma16(qf[ks], kf, s);
        }
        sa[fn] = s;
      }

      // online softmax; mask only the diagonal tile
      float p[4][4], mx[4];
      bool lastt = (it == qt);
#pragma unroll
      for (int r = 0; r < 4; r++) {
        int qrow = q0w + gl * 4 + r;
        float m = -1e30f;
        if (lastt) {
#pragma unroll
          for (int fn = 0; fn < 4; fn++) {
            int kkg = k0 + fn * 16 + lo;
            float v = (kkg <= qrow) ? sa[fn][r] : -1e30f;
            p[fn][r] = v;
            m = fmaxf(m, v);
          }
        } else {
#pragma unroll
          for (int fn = 0; fn < 4; fn++) {
            float v = sa[fn][r];
            p[fn][r] = v;
            m = fmaxf(m, v);
          }
        }
#pragma unroll
        for (int dlt = 1; dlt < 16; dlt <<= 1) m = fmaxf(m, __shfl_xor(m, dlt));
        mx[r] = m;
      }
      // defer-max: skip rescale when no significant growth (P bounded by 2^8)
      bool grow = !__all((mx[0] <= mrun[0] + 8.f) && (mx[1] <= mrun[1] + 8.f) &&
                         (mx[2] <= mrun[2] + 8.f) && (mx[3] <= mrun[3] + 8.f));
      if (grow) {
#pragma unroll
        for (int r = 0; r < 4; r++) {
          float mnew = fmaxf(mrun[r], mx[r]);
          float corr = exp2f(mrun[r] - mnew);
          mrun[r] = mnew;
          lrun[r] *= corr;
#pragma unroll
          for (int fd = 0; fd < 8; fd++) oacc[fd][r] *= corr;
        }
      }
#pragma unroll
      for (int r = 0; r < 4; r++) {
        float ls = 0.f;
#pragma unroll
        for (int fn = 0; fn < 4; fn++) {
          float pv = exp2f(p[fn][r] - mrun[r]);
          p[fn][r] = pv;
          ls += pv;
        }
#pragma unroll
        for (int dlt = 1; dlt < 16; dlt <<= 1) ls += __shfl_xor(ls, dlt);
        lrun[r] += ls;
      }

      // write P (bf16) to per-wave LDS, swizzled
#pragma unroll
      for (int fn = 0; fn < 4; fn++)
#pragma unroll
        for (int r = 0; r < 4; r++) {
          int qr = gl * 4 + r;
          int kc = fn * 16 + lo;
          Ps[wid][(qr * 8 + (((kc >> 3) ^ (qr & 7)))) * 8 + (kc & 7)] = f2bf(p[fn][r]);
        }

      // O += P V  (16 MFMAs)
#pragma unroll
      for (int ks2 = 0; ks2 < 2; ks2++) {
        bvec8 pf = *(const bvec8*)&Ps[wid][(lo * 8 + ((ks2 * 4 + gl) ^ (lo & 7))) * 8];
#pragma unroll
        for (int fd = 0; fd < 8; fd++) {
          int rd = fd * 16 + lo;
          int ck = ks2 * 4 + gl;
          bvec8 vf = *(const bvec8*)&Vs[(rd * 8 + (ck ^ (rd & 7))) * 8];
          oacc[fd] = mfma16(pf, vf, oacc[fd]);
        }
      }
      __syncthreads();
    }

    // epilogue: O / l -> yb [B][T][C]
#pragma unroll
    for (int r = 0; r < 4; r++) {
      int qrow = q0w + gl * 4 + r;
      float inv = 1.f / lrun[r];
#pragma unroll
      for (int fd = 0; fd < 8; fd++) {
        int d = fd * 16 + lo;
        yb[((size_t)b * TT + qrow) * CC + h * DD + d] = f2bf(oacc[fd][r] * inv);
      }
    }
  }
}

// ---------------- proj GEMM: [8192,2048]x[2048,2048]+bias -> fp32 out ----------------
__global__ __launch_bounds__(256) void k_gemm_proj(
    const unsigned short* __restrict__ A,    // yb [8192][2048]
    const unsigned short* __restrict__ Bt,   // w_proj^T [2048][2048]
    const float* __restrict__ bias,          // [2048]
    float* __restrict__ out) {               // [8192][2048]
  const int K = CC;
  __shared__ unsigned short As[128 * 32];
  __shared__ unsigned short Bs[128 * 32];
  int tid = threadIdx.x, wid = tid >> 6, ln = tid & 63;
  int gl = ln >> 4, lo = ln & 15;
  // XCD-aware bijective swizzle (grid = 16*64 = 1024, %8==0)
  unsigned nx = gridDim.x;
  unsigned orig = blockIdx.y * nx + blockIdx.x;
  unsigned cpx = (nx * gridDim.y) >> 3;
  unsigned wg = (orig & 7) * cpx + (orig >> 3);
  int m0 = (int)(wg / nx) * 128, n0 = (int)(wg % nx) * 128;
  int wr = wid >> 1, wc = wid & 1;
  fvec4 acc[4][4];
  fvec4 zero = {0.f, 0.f, 0.f, 0.f};
#pragma unroll
  for (int i = 0; i < 4; i++)
#pragma unroll
    for (int j = 0; j < 4; j++) acc[i][j] = zero;

  for (int k0 = 0; k0 < K; k0 += 32) {
#pragma unroll
    for (int j = 0; j < 2; j++) {
      int chunk = j * 256 + tid;
      int row = chunk >> 2, kc = chunk & 3;
      gload16(A + (size_t)(m0 + row) * K + k0 + kc * 8, &As[(j * 256 + wid * 64) * 8]);
    }
#pragma unroll
    for (int j = 0; j < 2; j++) {
      int chunk = j * 256 + tid;
      int row = chunk >> 2, kc = chunk & 3;
      gload16(Bt + (size_t)(n0 + row) * K + k0 + kc * 8, &Bs[(j * 256 + wid * 64) * 8]);
    }
    __syncthreads();
    bvec8 af[4], bf[4];
#pragma unroll
    for (int f = 0; f < 4; f++)
      af[f] = *(const bvec8*)&As[(wr * 64 + f * 16 + lo) * 32 + gl * 8];
#pragma unroll
    for (int f = 0; f < 4; f++)
      bf[f] = *(const bvec8*)&Bs[(wc * 64 + f * 16 + lo) * 32 + gl * 8];
#pragma unroll
    for (int i = 0; i < 4; i++)
#pragma unroll
      for (int j = 0; j < 4; j++) acc[i][j] = mfma16(af[i], bf[j], acc[i][j]);
    __syncthreads();
  }

#pragma unroll
  for (int fn = 0; fn < 4; fn++) {
    int n = n0 + wc * 64 + fn * 16 + lo;
    float bn = bias[n];
#pragma unroll
    for (int fm = 0; fm < 4; fm++) {
      int m = m0 + wr * 64 + fm * 16 + gl * 4;
#pragma unroll
      for (int r = 0; r < 4; r++) out[(size_t)(m + r) * CC + n] = acc[fm][fn][r] + bn;
    }
  }
}

extern "C" void kernel_launch(void* const* d_in, const int* in_sizes, int n_in,
                              void* d_out, int out_size, void* d_ws, size_t ws_size,
                              hipStream_t stream) {
  const float* x      = (const float*)d_in[0];
  const float* w_attn = (const float*)d_in[1];
  const float* b_attn = (const float*)d_in[2];
  const float* w_proj = (const float*)d_in[3];
  const float* b_proj = (const float*)d_in[4];
  float* out = (float*)d_out;

  char* ws = (char*)d_ws;
  unsigned short* xb    = (unsigned short*)(ws);                         // 32 MB
  unsigned short* wab_t = (unsigned short*)(ws + 33554432);              // 24 MB
  unsigned short* wpb_t = (unsigned short*)(ws + 58720256);              // 8 MB
  unsigned short* qkws  = (unsigned short*)(ws + 67108864);              // 64 MB
  unsigned short* vtws  = (unsigned short*)(ws + 134217728);             // 32 MB
  unsigned short* ybws  = (unsigned short*)(ws + 167772160);             // 32 MB

  hipLaunchKernelGGL(k_cvt, dim3(16384), dim3(256), 0, stream, x, xb, 4194304);
  hipLaunchKernelGGL(k_transpose, dim3(96, 32), dim3(256), 0, stream, w_attn, wab_t, 2048, 6144);
  hipLaunchKernelGGL(k_transpose, dim3(32, 32), dim3(256), 0, stream, w_proj, wpb_t, 2048, 2048);
  hipLaunchKernelGGL(k_gemm_qkv, dim3(48, 64), dim3(256), 0, stream, xb, wab_t, b_attn, qkws, vtws);
  hipLaunchKernelGGL(k_attn, dim3(1024), dim3(256), 0, stream, qkws, vtws, ybws);
  hipLaunchKernelGGL(k_gemm_proj, dim3(16, 64), dim3(256), 0, stream, ybws, wpb_t, b_proj, out);
}

// Round 3
// 509.411 us; speedup vs baseline: 1.5191x; 1.2173x over previous
//
#include <hip/hip_runtime.h>
#include <hip/hip_bf16.h>

#define NB 4
#define TT 2048
#define CC 2048
#define HH 16
#define DD 128

typedef short bvec8 __attribute__((ext_vector_type(8)));
typedef float fvec4 __attribute__((ext_vector_type(4)));

__device__ __forceinline__ void gload16(const void* g, void* l) {
  __builtin_amdgcn_global_load_lds(
      (__attribute__((address_space(1))) void*)g,
      (__attribute__((address_space(3))) void*)l, 16, 0, 0);
}

__device__ __forceinline__ unsigned short f2bf(float f) {
  union { float f; unsigned int u; } x; x.f = f;
  unsigned int u = x.u;
  return (unsigned short)((u + 0x7FFFu + ((u >> 16) & 1u)) >> 16);
}

__device__ __forceinline__ fvec4 mfma16(bvec8 a, bvec8 b, fvec4 c) {
  return __builtin_amdgcn_mfma_f32_16x16x32_bf16(a, b, c, 0, 0, 0);
}

// scale * log2(e), folded into K at the QKV epilogue
#define KSC (0.08838834764831845f * 1.4426950408889634f)

// ---------------- convert fp32 -> bf16 (vectorized) ----------------
__global__ __launch_bounds__(256) void k_cvt(const float* __restrict__ in,
                                             unsigned short* __restrict__ out, int n4) {
  int i = blockIdx.x * 256 + threadIdx.x;
  if (i >= n4) return;
  float4 v = ((const float4*)in)[i];
  ushort4 o;
  o.x = f2bf(v.x); o.y = f2bf(v.y); o.z = f2bf(v.z); o.w = f2bf(v.w);
  ((ushort4*)out)[i] = o;
}

// ---------------- transpose fp32 [R][Cn] -> bf16 [Cn][R] ----------------
__global__ __launch_bounds__(256) void k_transpose(const float* __restrict__ in,
                                                   unsigned short* __restrict__ out,
                                                   int R, int Cn) {
  __shared__ unsigned short tile[64][65];
  int tC = blockIdx.x * 64, tR = blockIdx.y * 64;
  int t = threadIdx.x;
  for (int i = 0; i < 16; i++) {
    int idx = t + i * 256; int r = idx >> 6, c = idx & 63;
    tile[r][c] = f2bf(in[(size_t)(tR + r) * Cn + tC + c]);
  }
  __syncthreads();
  for (int i = 0; i < 16; i++) {
    int idx = t + i * 256; int r = idx >> 6, c = idx & 63;
    out[(size_t)(tC + r) * R + tR + c] = tile[c][r];
  }
}

// ============ 256x256 8-phase GEMM (BK=64, 8 waves, dbuf 128KiB LDS) ============
// A [M][K] bf16, Bt [N][K] bf16. EPI=0: QKV epilogue; EPI=1: proj fp32 epilogue.
template <int EPI>
__global__ __launch_bounds__(512, 2) void k_gemm8(
    const unsigned short* __restrict__ A,
    const unsigned short* __restrict__ Bt,
    const float* __restrict__ bias,
    unsigned short* __restrict__ qk,   // EPI=0
    unsigned short* __restrict__ vt,   // EPI=0
    float* __restrict__ out) {         // EPI=1
  const int K = CC;
  const int nt = K / 64;               // 32 K-tiles
  // per buffer: A tile [256][64] @ 0 (16384 ush), B tile [256][64] @ 16384
  __shared__ unsigned short sm[2][32768];

  int tid = threadIdx.x;
  int wid = tid >> 6, ln = tid & 63, gl = ln >> 4, lo = ln & 15;
  int wr = wid >> 2, wc = wid & 3;     // 2 (M) x 4 (N) waves

  // XCD-aware bijective swizzle (grid %8 == 0)
  unsigned nx = gridDim.x;
  unsigned orig = blockIdx.y * nx + blockIdx.x;
  unsigned cpx = (nx * gridDim.y) >> 3;
  unsigned wg = (orig & 7) * cpx + (orig >> 3);
  int m0 = (int)(wg / nx) * 256, n0 = (int)(wg % nx) * 256;

  // stage one half-tile (128 rows x 64 cols) of A or B; 2 gload_lds per thread.
  // LDS chunk c holds global (r = c>>3, kc = (c&7) ^ (r&7))  [chunk = 16B]
  auto stageA = [&](int buf, int half, int kt) {
#pragma unroll
    for (int j = 0; j < 2; j++) {
      int c = j * 512 + tid;
      int r = c >> 3;
      int kc = (c & 7) ^ (r & 7);
      gload16(A + (size_t)(m0 + half * 128 + r) * K + kt * 64 + kc * 8,
              &sm[buf][(size_t)(half * 1024 + c) * 8]);
    }
  };
  auto stageB = [&](int buf, int half, int kt) {
#pragma unroll
    for (int j = 0; j < 2; j++) {
      int c = j * 512 + tid;
      int r = c >> 3;
      int kc = (c & 7) ^ (r & 7);
      gload16(Bt + (size_t)(n0 + half * 128 + r) * K + kt * 64 + kc * 8,
              &sm[buf][16384 + (size_t)(half * 1024 + c) * 8]);
    }
  };

  // fragment read offsets: row&7 == lo&7 for both A and B
#define AFRAG(buf, mi, ks) \
  (*(const bvec8*)&sm[buf][(((wr * 128 + (mi) * 16 + lo) * 8) + ((((ks) * 4 + gl)) ^ (lo & 7))) * 8])
#define BFRAG(buf, nj, ks) \
  (*(const bvec8*)&sm[buf][16384 + (((wc * 64 + (nj) * 16 + lo) * 8) + ((((ks) * 4 + gl)) ^ (lo & 7))) * 8])

  fvec4 acc[8][4];
  fvec4 zero = {0.f, 0.f, 0.f, 0.f};
#pragma unroll
  for (int i = 0; i < 8; i++)
#pragma unroll
    for (int j = 0; j < 4; j++) acc[i][j] = zero;

  // prologue: K-tile 0 fully, K-tile 1 A-halves  (12 loads; keep 4 in flight)
  stageA(0, 0, 0); stageA(0, 1, 0); stageB(0, 0, 0); stageB(0, 1, 0);
  stageA(1, 0, 1); stageA(1, 1, 1);
  asm volatile("s_waitcnt vmcnt(4)" ::: "memory");
  __builtin_amdgcn_sched_barrier(0);
  __builtin_amdgcn_s_barrier();

  for (int t = 0; t < nt; t++) {
    int cur = t & 1;
    bvec8 a0[4], a1[4], a2[4], a3[4], b0[4], b1[4];

    // ---- P1: read A(mi0-3,ks0)+B(ks0); stage (t+1).Bh0; MFMA q1
#pragma unroll
    for (int mi = 0; mi < 4; mi++) a0[mi] = AFRAG(cur, mi, 0);
#pragma unroll
    for (int nj = 0; nj < 4; nj++) b0[nj] = BFRAG(cur, nj, 0);
    if (t + 1 < nt) stageB(cur ^ 1, 0, t + 1);
    __builtin_amdgcn_s_barrier();
    asm volatile("s_waitcnt lgkmcnt(0)" ::: "memory");
    __builtin_amdgcn_sched_barrier(0);
    __builtin_amdgcn_s_setprio(1);
#pragma unroll
    for (int mi = 0; mi < 4; mi++)
#pragma unroll
      for (int nj = 0; nj < 4; nj++) acc[mi][nj] = mfma16(a0[mi], b0[nj], acc[mi][nj]);
    __builtin_amdgcn_s_setprio(0);
    __builtin_amdgcn_s_barrier();

    // ---- P2: read A(mi4-7,ks0)+B(ks1); stage (t+1).Bh1; MFMA q2
#pragma unroll
    for (int mi = 0; mi < 4; mi++) a1[mi] = AFRAG(cur, mi + 4, 0);
#pragma unroll
    for (int nj = 0; nj < 4; nj++) b1[nj] = BFRAG(cur, nj, 1);
    if (t + 1 < nt) stageB(cur ^ 1, 1, t + 1);
    __builtin_amdgcn_s_barrier();
    asm volatile("s_waitcnt lgkmcnt(0)" ::: "memory");
    __builtin_amdgcn_sched_barrier(0);
    __builtin_amdgcn_s_setprio(1);
#pragma unroll
    for (int mi = 0; mi < 4; mi++)
#pragma unroll
      for (int nj = 0; nj < 4; nj++) acc[mi + 4][nj] = mfma16(a1[mi], b0[nj], acc[mi + 4][nj]);
    __builtin_amdgcn_s_setprio(0);
    __builtin_amdgcn_s_barrier();

    // ---- P3: read A(mi0-7,ks1); MFMA q3. lgkm0 drains ALL our LDS reads of buf[cur].
#pragma unroll
    for (int mi = 0; mi < 4; mi++) a2[mi] = AFRAG(cur, mi, 1);
#pragma unroll
    for (int mi = 0; mi < 4; mi++) a3[mi] = AFRAG(cur, mi + 4, 1);
    __builtin_amdgcn_s_barrier();
    asm volatile("s_waitcnt lgkmcnt(0)" ::: "memory");
    __builtin_amdgcn_sched_barrier(0);
    __builtin_amdgcn_s_setprio(1);
#pragma unroll
    for (int mi = 0; mi < 4; mi++)
#pragma unroll
      for (int nj = 0; nj < 4; nj++) acc[mi][nj] = mfma16(a2[mi], b1[nj], acc[mi][nj]);
    __builtin_amdgcn_s_setprio(0);
    __builtin_amdgcn_s_barrier();
    // after this barrier every wave's reads of buf[cur] are complete -> safe to overwrite its A

    // ---- P4: stage (t+2).Ah0+Ah1 into buf[cur]; vmcnt(4) -> tile t+1 fully landed; MFMA q4
    if (t + 2 < nt) { stageA(cur, 0, t + 2); stageA(cur, 1, t + 2); }
    if (t + 2 < nt) {
      asm volatile("s_waitcnt vmcnt(4)" ::: "memory");
    } else {
      asm volatile("s_waitcnt vmcnt(0)" ::: "memory");
    }
    __builtin_amdgcn_sched_barrier(0);
    __builtin_amdgcn_s_barrier();
    __builtin_amdgcn_s_setprio(1);
#pragma unroll
    for (int mi = 0; mi < 4; mi++)
#pragma unroll
      for (int nj = 0; nj < 4; nj++) acc[mi + 4][nj] = mfma16(a3[mi], b1[nj], acc[mi + 4][nj]);
    __builtin_amdgcn_s_setprio(0);
    __builtin_amdgcn_s_barrier();
  }

  // ---------------- epilogue ----------------
  if (EPI == 0) {
#pragma unroll
    for (int nj = 0; nj < 4; nj++) {
      int n = n0 + wc * 64 + nj * 16 + lo;
      float bn = bias[n];
      int s = n >> 11, hh = (n >> 7) & 15, d = n & 127;
      float mulv = (s == 1) ? KSC : 1.0f;  // pre-scale K by scale*log2e
#pragma unroll
      for (int mi = 0; mi < 8; mi++) {
        int mb = m0 + wr * 128 + mi * 16 + gl * 4;
        int b = mb >> 11, t0 = mb & 2047;
        if (s < 2) {
          size_t base = ((((size_t)s * NB + b) * HH + hh) * TT) * DD;
#pragma unroll
          for (int r = 0; r < 4; r++)
            qk[base + (size_t)(t0 + r) * DD + d] = f2bf((acc[mi][nj][r] + bn) * mulv);
        } else {
          size_t base = (((size_t)b * HH + hh) * DD + d) * TT + t0;
          ushort4 o;
          o.x = f2bf(acc[mi][nj][0] + bn);
          o.y = f2bf(acc[mi][nj][1] + bn);
          o.z = f2bf(acc[mi][nj][2] + bn);
          o.w = f2bf(acc[mi][nj][3] + bn);
          *(ushort4*)&vt[base] = o;
        }
      }
    }
  } else {
#pragma unroll
    for (int nj = 0; nj < 4; nj++) {
      int n = n0 + wc * 64 + nj * 16 + lo;
      float bn = bias[n];
#pragma unroll
      for (int mi = 0; mi < 8; mi++) {
        int m = m0 + wr * 128 + mi * 16 + gl * 4;
#pragma unroll
        for (int r = 0; r < 4; r++) out[(size_t)(m + r) * CC + n] = acc[mi][nj][r] + bn;
      }
    }
  }
#undef AFRAG
#undef BFRAG
}

// ---------------- flash attention (causal), paired q-tiles (qt, 31-qt) per block ----------------
__global__ __launch_bounds__(256) void k_attn(
    const unsigned short* __restrict__ qk,   // [2][B][H][T][D], K pre-scaled
    const unsigned short* __restrict__ vt,   // [B][H][D][T]
    unsigned short* __restrict__ yb) {       // [B][T][C]
  __shared__ unsigned short Ks[64 * 128];    // [kk][d], chunk-swizzled
  __shared__ unsigned short Vs[128 * 64];    // [d][kk], chunk-swizzled
  __shared__ unsigned short Ps[4][16 * 64];  // per-wave P, chunk-swizzled
  int tid = threadIdx.x, wid = tid >> 6, ln = tid & 63;
  int gl = ln >> 4, lo = ln & 15;
  int qp = blockIdx.x & 15;                  // pair index 0..15
  int bh = blockIdx.x >> 4;
  int b = bh >> 4, h = bh & 15;
  const unsigned short* Q  = qk + (((size_t)b * HH + h) * TT) * DD;
  const unsigned short* Kg = qk + ((((size_t)NB + b) * HH + h) * TT) * DD;
  const unsigned short* Vg = vt + (((size_t)b * HH + h) * DD) * TT;
  fvec4 zero = {0.f, 0.f, 0.f, 0.f};

  for (int pass = 0; pass < 2; pass++) {
    int qt = pass ? (31 - qp) : qp;          // combined work = 33 tiles, all blocks equal
    int q0w = qt * 64 + wid * 16;

    bvec8 qf[4];
#pragma unroll
    for (int ks = 0; ks < 4; ks++)
      qf[ks] = *(const bvec8*)(Q + (size_t)(q0w + lo) * DD + ks * 32 + gl * 8);

    fvec4 oacc[8];
#pragma unroll
    for (int i = 0; i < 8; i++) oacc[i] = zero;
    float mrun[4] = {-1e30f, -1e30f, -1e30f, -1e30f};
    float lrun[4] = {0.f, 0.f, 0.f, 0.f};

    int ntiles = qt + 1;
    for (int it = 0; it < ntiles; it++) {
      int k0 = it * 64;
      // stage K tile [64][128] and V^T tile [128][64], chunk-XOR swizzled
#pragma unroll
      for (int j = 0; j < 4; j++) {
        int c = j * 256 + tid;
        int r = c >> 4, cc = c & 15;
        gload16(Kg + (size_t)(k0 + r) * DD + ((cc ^ (r & 7)) * 8), &Ks[(j * 256 + wid * 64) * 8]);
      }
#pragma unroll
      for (int j = 0; j < 4; j++) {
        int c = j * 256 + tid;
        int r = c >> 3, cc = c & 7;
        gload16(Vg + (size_t)r * TT + k0 + ((cc ^ (r & 7)) * 8), &Vs[(j * 256 + wid * 64) * 8]);
      }
      __syncthreads();

      // S = Q K^T  (16 MFMAs); K is pre-scaled so S is already in log2 units
      fvec4 sa[4];
#pragma unroll
      for (int fn = 0; fn < 4; fn++) {
        fvec4 s = zero;
#pragma unroll
        for (int ks = 0; ks < 4; ks++) {
          int r = fn * 16 + lo;
          int cd = ks * 4 + gl;
          bvec8 kf = *(const bvec8*)&Ks[(r * 16 + (cd ^ (r & 7))) * 8];
          s = mfma16(qf[ks], kf, s);
        }
        sa[fn] = s;
      }

      // online softmax; mask only the diagonal tile
      float p[4][4], mx[4];
      bool lastt = (it == qt);
#pragma unroll
      for (int r = 0; r < 4; r++) {
        int qrow = q0w + gl * 4 + r;
        float m = -1e30f;
        if (lastt) {
#pragma unroll
          for (int fn = 0; fn < 4; fn++) {
            int kkg = k0 + fn * 16 + lo;
            float v = (kkg <= qrow) ? sa[fn][r] : -1e30f;
            p[fn][r] = v;
            m = fmaxf(m, v);
          }
        } else {
#pragma unroll
          for (int fn = 0; fn < 4; fn++) {
            float v = sa[fn][r];
            p[fn][r] = v;
            m = fmaxf(m, v);
          }
        }
#pragma unroll
        for (int dlt = 1; dlt < 16; dlt <<= 1) m = fmaxf(m, __shfl_xor(m, dlt));
        mx[r] = m;
      }
      // defer-max: skip rescale when no significant growth (P bounded by 2^8)
      bool grow = !__all((mx[0] <= mrun[0] + 8.f) && (mx[1] <= mrun[1] + 8.f) &&
                         (mx[2] <= mrun[2] + 8.f) && (mx[3] <= mrun[3] + 8.f));
      if (grow) {
#pragma unroll
        for (int r = 0; r < 4; r++) {
          float mnew = fmaxf(mrun[r], mx[r]);
          float corr = exp2f(mrun[r] - mnew);
          mrun[r] = mnew;
          lrun[r] *= corr;
#pragma unroll
          for (int fd = 0; fd < 8; fd++) oacc[fd][r] *= corr;
        }
      }
#pragma unroll
      for (int r = 0; r < 4; r++) {
        float ls = 0.f;
#pragma unroll
        for (int fn = 0; fn < 4; fn++) {
          float pv = exp2f(p[fn][r] - mrun[r]);
          p[fn][r] = pv;
          ls += pv;
        }
#pragma unroll
        for (int dlt = 1; dlt < 16; dlt <<= 1) ls += __shfl_xor(ls, dlt);
        lrun[r] += ls;
      }

      // write P (bf16) to per-wave LDS, swizzled
#pragma unroll
      for (int fn = 0; fn < 4; fn++)
#pragma unroll
        for (int r = 0; r < 4; r++) {
          int qr = gl * 4 + r;
          int kc = fn * 16 + lo;
          Ps[wid][(qr * 8 + (((kc >> 3) ^ (qr & 7)))) * 8 + (kc & 7)] = f2bf(p[fn][r]);
        }

      // O += P V  (16 MFMAs)
#pragma unroll
      for (int ks2 = 0; ks2 < 2; ks2++) {
        bvec8 pf = *(const bvec8*)&Ps[wid][(lo * 8 + ((ks2 * 4 + gl) ^ (lo & 7))) * 8];
#pragma unroll
        for (int fd = 0; fd < 8; fd++) {
          int rd = fd * 16 + lo;
          int ck = ks2 * 4 + gl;
          bvec8 vf = *(const bvec8*)&Vs[(rd * 8 + (ck ^ (rd & 7))) * 8];
          oacc[fd] = mfma16(pf, vf, oacc[fd]);
        }
      }
      __syncthreads();
    }

    // epilogue: O / l -> yb [B][T][C]
#pragma unroll
    for (int r = 0; r < 4; r++) {
      int qrow = q0w + gl * 4 + r;
      float inv = 1.f / lrun[r];
#pragma unroll
      for (int fd = 0; fd < 8; fd++) {
        int d = fd * 16 + lo;
        yb[((size_t)b * TT + qrow) * CC + h * DD + d] = f2bf(oacc[fd][r] * inv);
      }
    }
  }
}

extern "C" void kernel_launch(void* const* d_in, const int* in_sizes, int n_in,
                              void* d_out, int out_size, void* d_ws, size_t ws_size,
                              hipStream_t stream) {
  const float* x      = (const float*)d_in[0];
  const float* w_attn = (const float*)d_in[1];
  const float* b_attn = (const float*)d_in[2];
  const float* w_proj = (const float*)d_in[3];
  const float* b_proj = (const float*)d_in[4];
  float* out = (float*)d_out;

  char* ws = (char*)d_ws;
  unsigned short* xb    = (unsigned short*)(ws);                         // 32 MB
  unsigned short* wab_t = (unsigned short*)(ws + 33554432);              // 24 MB
  unsigned short* wpb_t = (unsigned short*)(ws + 58720256);              // 8 MB
  unsigned short* qkws  = (unsigned short*)(ws + 67108864);              // 64 MB
  unsigned short* vtws  = (unsigned short*)(ws + 134217728);             // 32 MB
  unsigned short* ybws  = (unsigned short*)(ws + 167772160);             // 32 MB

  hipLaunchKernelGGL(k_cvt, dim3(16384), dim3(256), 0, stream, x, xb, 4194304);
  hipLaunchKernelGGL(k_transpose, dim3(96, 32), dim3(256), 0, stream, w_attn, wab_t, 2048, 6144);
  hipLaunchKernelGGL(k_transpose, dim3(32, 32), dim3(256), 0, stream, w_proj, wpb_t, 2048, 2048);
  hipLaunchKernelGGL((k_gemm8<0>), dim3(24, 32), dim3(512), 0, stream,
                     xb, wab_t, b_attn, qkws, vtws, (float*)nullptr);
  hipLaunchKernelGGL(k_attn, dim3(1024), dim3(256), 0, stream, qkws, vtws, ybws);
  hipLaunchKernelGGL((k_gemm8<1>), dim3(8, 32), dim3(512), 0, stream,
                     ybws, wpb_t, b_proj, (unsigned short*)nullptr, (unsigned short*)nullptr, out);
}

// Round 4
// 480.356 us; speedup vs baseline: 1.6109x; 1.0605x over previous
//
#include <hip/hip_runtime.h>
#include <hip/hip_bf16.h>

#define NB 4
#define TT 2048
#define CC 2048
#define HH 16
#define DD 128

typedef short bvec8 __attribute__((ext_vector_type(8)));
typedef float fvec4 __attribute__((ext_vector_type(4)));

__device__ __forceinline__ void gload16(const void* g, void* l) {
  __builtin_amdgcn_global_load_lds(
      (__attribute__((address_space(1))) void*)g,
      (__attribute__((address_space(3))) void*)l, 16, 0, 0);
}

__device__ __forceinline__ unsigned short f2bf(float f) {
  union { float f; unsigned int u; } x; x.f = f;
  unsigned int u = x.u;
  return (unsigned short)((u + 0x7FFFu + ((u >> 16) & 1u)) >> 16);
}

__device__ __forceinline__ fvec4 mfma16(bvec8 a, bvec8 b, fvec4 c) {
  return __builtin_amdgcn_mfma_f32_16x16x32_bf16(a, b, c, 0, 0, 0);
}

// scale * log2(e), folded into K at the QKV epilogue
#define KSC (0.08838834764831845f * 1.4426950408889634f)

// ---------------- convert fp32 -> bf16 (vectorized) ----------------
__global__ __launch_bounds__(256) void k_cvt(const float* __restrict__ in,
                                             unsigned short* __restrict__ out, int n4) {
  int i = blockIdx.x * 256 + threadIdx.x;
  if (i >= n4) return;
  float4 v = ((const float4*)in)[i];
  ushort4 o;
  o.x = f2bf(v.x); o.y = f2bf(v.y); o.z = f2bf(v.z); o.w = f2bf(v.w);
  ((ushort4*)out)[i] = o;
}

// ---------------- transpose fp32 [R][Cn] -> bf16 [Cn][R] ----------------
__global__ __launch_bounds__(256) void k_transpose(const float* __restrict__ in,
                                                   unsigned short* __restrict__ out,
                                                   int R, int Cn) {
  __shared__ unsigned short tile[64][65];
  int tC = blockIdx.x * 64, tR = blockIdx.y * 64;
  int t = threadIdx.x;
  for (int i = 0; i < 16; i++) {
    int idx = t + i * 256; int r = idx >> 6, c = idx & 63;
    tile[r][c] = f2bf(in[(size_t)(tR + r) * Cn + tC + c]);
  }
  __syncthreads();
  for (int i = 0; i < 16; i++) {
    int idx = t + i * 256; int r = idx >> 6, c = idx & 63;
    out[(size_t)(tC + r) * R + tR + c] = tile[c][r];
  }
}

// ============ 256x256 8-phase GEMM (BK=64, 8 waves, dbuf 128KiB LDS) ============
// A [M][K] bf16, Bt [N][K] bf16. EPI=0: QKV epilogue; EPI=1: proj fp32 epilogue.
// V output layout: vt[b][h][t/8][d][8]  (d-major, 8-wide t tiles -> coalesced both sides)
template <int EPI>
__global__ __launch_bounds__(512, 2) void k_gemm8(
    const unsigned short* __restrict__ A,
    const unsigned short* __restrict__ Bt,
    const float* __restrict__ bias,
    unsigned short* __restrict__ qk,   // EPI=0
    unsigned short* __restrict__ vt,   // EPI=0
    float* __restrict__ out) {         // EPI=1
  const int K = CC;
  const int nt = K / 64;               // 32 K-tiles
  __shared__ unsigned short sm[2][32768];

  int tid = threadIdx.x;
  int wid = tid >> 6, ln = tid & 63, gl = ln >> 4, lo = ln & 15;
  int wr = wid >> 2, wc = wid & 3;     // 2 (M) x 4 (N) waves

  unsigned nx = gridDim.x;
  unsigned orig = blockIdx.y * nx + blockIdx.x;
  unsigned cpx = (nx * gridDim.y) >> 3;
  unsigned wg = (orig & 7) * cpx + (orig >> 3);
  int m0 = (int)(wg / nx) * 256, n0 = (int)(wg % nx) * 256;

  auto stageA = [&](int buf, int half, int kt) {
#pragma unroll
    for (int j = 0; j < 2; j++) {
      int c = j * 512 + tid;
      int r = c >> 3;
      int kc = (c & 7) ^ (r & 7);
      gload16(A + (size_t)(m0 + half * 128 + r) * K + kt * 64 + kc * 8,
              &sm[buf][(size_t)(half * 1024 + c) * 8]);
    }
  };
  auto stageB = [&](int buf, int half, int kt) {
#pragma unroll
    for (int j = 0; j < 2; j++) {
      int c = j * 512 + tid;
      int r = c >> 3;
      int kc = (c & 7) ^ (r & 7);
      gload16(Bt + (size_t)(n0 + half * 128 + r) * K + kt * 64 + kc * 8,
              &sm[buf][16384 + (size_t)(half * 1024 + c) * 8]);
    }
  };

#define AFRAG(buf, mi, ks) \
  (*(const bvec8*)&sm[buf][(((wr * 128 + (mi) * 16 + lo) * 8) + ((((ks) * 4 + gl)) ^ (lo & 7))) * 8])
#define BFRAG(buf, nj, ks) \
  (*(const bvec8*)&sm[buf][16384 + (((wc * 64 + (nj) * 16 + lo) * 8) + ((((ks) * 4 + gl)) ^ (lo & 7))) * 8])

  fvec4 acc[8][4];
  fvec4 zero = {0.f, 0.f, 0.f, 0.f};
#pragma unroll
  for (int i = 0; i < 8; i++)
#pragma unroll
    for (int j = 0; j < 4; j++) acc[i][j] = zero;

  stageA(0, 0, 0); stageA(0, 1, 0); stageB(0, 0, 0); stageB(0, 1, 0);
  stageA(1, 0, 1); stageA(1, 1, 1);
  asm volatile("s_waitcnt vmcnt(4)" ::: "memory");
  __builtin_amdgcn_sched_barrier(0);
  __builtin_amdgcn_s_barrier();

  for (int t = 0; t < nt; t++) {
    int cur = t & 1;
    bvec8 a0[4], a1[4], a2[4], a3[4], b0[4], b1[4];

    // ---- P1
#pragma unroll
    for (int mi = 0; mi < 4; mi++) a0[mi] = AFRAG(cur, mi, 0);
#pragma unroll
    for (int nj = 0; nj < 4; nj++) b0[nj] = BFRAG(cur, nj, 0);
    if (t + 1 < nt) stageB(cur ^ 1, 0, t + 1);
    __builtin_amdgcn_s_barrier();
    asm volatile("s_waitcnt lgkmcnt(0)" ::: "memory");
    __builtin_amdgcn_sched_barrier(0);
    __builtin_amdgcn_s_setprio(1);
#pragma unroll
    for (int mi = 0; mi < 4; mi++)
#pragma unroll
      for (int nj = 0; nj < 4; nj++) acc[mi][nj] = mfma16(a0[mi], b0[nj], acc[mi][nj]);
    __builtin_amdgcn_s_setprio(0);
    __builtin_amdgcn_s_barrier();

    // ---- P2
#pragma unroll
    for (int mi = 0; mi < 4; mi++) a1[mi] = AFRAG(cur, mi + 4, 0);
#pragma unroll
    for (int nj = 0; nj < 4; nj++) b1[nj] = BFRAG(cur, nj, 1);
    if (t + 1 < nt) stageB(cur ^ 1, 1, t + 1);
    __builtin_amdgcn_s_barrier();
    asm volatile("s_waitcnt lgkmcnt(0)" ::: "memory");
    __builtin_amdgcn_sched_barrier(0);
    __builtin_amdgcn_s_setprio(1);
#pragma unroll
    for (int mi = 0; mi < 4; mi++)
#pragma unroll
      for (int nj = 0; nj < 4; nj++) acc[mi + 4][nj] = mfma16(a1[mi], b0[nj], acc[mi + 4][nj]);
    __builtin_amdgcn_s_setprio(0);
    __builtin_amdgcn_s_barrier();

    // ---- P3
#pragma unroll
    for (int mi = 0; mi < 4; mi++) a2[mi] = AFRAG(cur, mi, 1);
#pragma unroll
    for (int mi = 0; mi < 4; mi++) a3[mi] = AFRAG(cur, mi + 4, 1);
    __builtin_amdgcn_s_barrier();
    asm volatile("s_waitcnt lgkmcnt(0)" ::: "memory");
    __builtin_amdgcn_sched_barrier(0);
    __builtin_amdgcn_s_setprio(1);
#pragma unroll
    for (int mi = 0; mi < 4; mi++)
#pragma unroll
      for (int nj = 0; nj < 4; nj++) acc[mi][nj] = mfma16(a2[mi], b1[nj], acc[mi][nj]);
    __builtin_amdgcn_s_setprio(0);
    __builtin_amdgcn_s_barrier();

    // ---- P4
    if (t + 2 < nt) { stageA(cur, 0, t + 2); stageA(cur, 1, t + 2); }
    if (t + 2 < nt) {
      asm volatile("s_waitcnt vmcnt(4)" ::: "memory");
    } else {
      asm volatile("s_waitcnt vmcnt(0)" ::: "memory");
    }
    __builtin_amdgcn_sched_barrier(0);
    __builtin_amdgcn_s_barrier();
    __builtin_amdgcn_s_setprio(1);
#pragma unroll
    for (int mi = 0; mi < 4; mi++)
#pragma unroll
      for (int nj = 0; nj < 4; nj++) acc[mi + 4][nj] = mfma16(a3[mi], b1[nj], acc[mi + 4][nj]);
    __builtin_amdgcn_s_setprio(0);
    __builtin_amdgcn_s_barrier();
  }

  // ---------------- epilogue ----------------
  if (EPI == 0) {
#pragma unroll
    for (int nj = 0; nj < 4; nj++) {
      int n = n0 + wc * 64 + nj * 16 + lo;
      float bn = bias[n];
      int s = n >> 11, hh = (n >> 7) & 15, d = n & 127;
      float mulv = (s == 1) ? KSC : 1.0f;
#pragma unroll
      for (int mi = 0; mi < 8; mi++) {
        int mb = m0 + wr * 128 + mi * 16 + gl * 4;
        int b = mb >> 11, t0 = mb & 2047;
        if (s < 2) {
          size_t base = ((((size_t)s * NB + b) * HH + hh) * TT) * DD;
#pragma unroll
          for (int r = 0; r < 4; r++)
            qk[base + (size_t)(t0 + r) * DD + d] = f2bf((acc[mi][nj][r] + bn) * mulv);
        } else {
          // vt[b][h][t/8][d][8]; t0 is a multiple of 4 -> 4 consecutive ushorts
          size_t base = ((((size_t)b * HH + hh) * (TT / 8) + (t0 >> 3)) * DD + d) * 8 + (t0 & 7);
          ushort4 o;
          o.x = f2bf(acc[mi][nj][0] + bn);
          o.y = f2bf(acc[mi][nj][1] + bn);
          o.z = f2bf(acc[mi][nj][2] + bn);
          o.w = f2bf(acc[mi][nj][3] + bn);
          *(ushort4*)&vt[base] = o;
        }
      }
    }
  } else {
#pragma unroll
    for (int nj = 0; nj < 4; nj++) {
      int n = n0 + wc * 64 + nj * 16 + lo;
      float bn = bias[n];
#pragma unroll
      for (int mi = 0; mi < 8; mi++) {
        int m = m0 + wr * 128 + mi * 16 + gl * 4;
#pragma unroll
        for (int r = 0; r < 4; r++) out[(size_t)(m + r) * CC + n] = acc[mi][nj][r] + bn;
      }
    }
  }
#undef AFRAG
#undef BFRAG
}

// ---------------- flash attention (causal), paired q-tiles, dbuf pipelined ----------------
__global__ __launch_bounds__(256) void k_attn(
    const unsigned short* __restrict__ qk,   // [2][B][H][T][D], K pre-scaled
    const unsigned short* __restrict__ vt,   // [B][H][T/8][D][8]
    unsigned short* __restrict__ yb) {       // [B][T][C]
  __shared__ unsigned short Ks[2][8192];     // [kk][d] chunks, XOR-swizzled
  __shared__ unsigned short Vs[2][8192];     // [ck][d] chunks, linear
  __shared__ unsigned short Ps[4][1024];     // per-wave P, chunk-swizzled
  int tid = threadIdx.x, wid = tid >> 6, ln = tid & 63;
  int gl = ln >> 4, lo = ln & 15;
  int qp = blockIdx.x & 15;                  // pair index 0..15
  int bh = blockIdx.x >> 4;
  int b = bh >> 4, h = bh & 15;
  const unsigned short* Q  = qk + (((size_t)b * HH + h) * TT) * DD;
  const unsigned short* Kg = qk + ((((size_t)NB + b) * HH + h) * TT) * DD;
  const unsigned short* Vg = vt + (((size_t)b * HH + h) * (TT / 8)) * DD * 8;
  fvec4 zero = {0.f, 0.f, 0.f, 0.f};

  auto stage = [&](int buf, int it) {
    int k0 = it * 64;
#pragma unroll
    for (int j = 0; j < 4; j++) {
      int c = j * 256 + tid;
      int r = c >> 4, cc = c & 15;
      gload16(Kg + (size_t)(k0 + r) * DD + ((cc ^ (r & 7)) * 8), &Ks[buf][(j * 256 + wid * 64) * 8]);
    }
#pragma unroll
    for (int j = 0; j < 4; j++) {
      int c = j * 256 + tid;
      int cc = c >> 7, d = c & 127;
      gload16(Vg + ((size_t)(k0 / 8 + cc) * DD + d) * 8, &Vs[buf][(j * 256 + wid * 64) * 8]);
    }
  };

  for (int pass = 0; pass < 2; pass++) {
    int qt = pass ? (31 - qp) : qp;          // combined work = 33 tiles, all blocks equal
    int q0w = qt * 64 + wid * 16;

    bvec8 qf[4];
#pragma unroll
    for (int ks = 0; ks < 4; ks++)
      qf[ks] = *(const bvec8*)(Q + (size_t)(q0w + lo) * DD + ks * 32 + gl * 8);

    fvec4 oacc[8];
#pragma unroll
    for (int i = 0; i < 8; i++) oacc[i] = zero;
    float mrun[4] = {-1e30f, -1e30f, -1e30f, -1e30f};
    float lrun[4] = {0.f, 0.f, 0.f, 0.f};   // per-lane column partials

    int ntiles = qt + 1;
    // prologue: stage tile 0
    stage(0, 0);
    asm volatile("s_waitcnt vmcnt(0)" ::: "memory");
    __builtin_amdgcn_sched_barrier(0);
    __builtin_amdgcn_s_barrier();
    __builtin_amdgcn_sched_barrier(0);

    for (int it = 0; it < ntiles; it++) {
      int cur = it & 1;
      int k0 = it * 64;
      if (it + 1 < ntiles) stage(cur ^ 1, it + 1);

      // S = Q K^T  (16 MFMAs); K pre-scaled so S is in log2 units
      fvec4 sa[4];
#pragma unroll
      for (int fn = 0; fn < 4; fn++) {
        fvec4 s = zero;
#pragma unroll
        for (int ks = 0; ks < 4; ks++) {
          int r = fn * 16 + lo;
          int cd = ks * 4 + gl;
          bvec8 kf = *(const bvec8*)&Ks[cur][(r * 16 + (cd ^ (r & 7))) * 8];
          s = mfma16(qf[ks], kf, s);
        }
        sa[fn] = s;
      }

      // per-lane p + per-lane max; mask only diagonal tile
      float p[4][4], mxl[4];
      bool lastt = (it == qt);
#pragma unroll
      for (int r = 0; r < 4; r++) {
        int qrow = q0w + gl * 4 + r;
        float m = -1e30f;
        if (lastt) {
#pragma unroll
          for (int fn = 0; fn < 4; fn++) {
            int kkg = k0 + fn * 16 + lo;
            float v = (kkg <= qrow) ? sa[fn][r] : -1e30f;
            p[fn][r] = v;
            m = fmaxf(m, v);
          }
        } else {
#pragma unroll
          for (int fn = 0; fn < 4; fn++) {
            float v = sa[fn][r];
            p[fn][r] = v;
            m = fmaxf(m, v);
          }
        }
        mxl[r] = m;
      }
      // defer-max: full reduce + rescale only when some lane exceeds threshold
      bool c = (mxl[0] > mrun[0] + 8.f) || (mxl[1] > mrun[1] + 8.f) ||
               (mxl[2] > mrun[2] + 8.f) || (mxl[3] > mrun[3] + 8.f);
      if (__any(c)) {
#pragma unroll
        for (int r = 0; r < 4; r++) {
          float m = mxl[r];
#pragma unroll
          for (int dlt = 1; dlt < 16; dlt <<= 1) m = fmaxf(m, __shfl_xor(m, dlt));
          float mnew = fmaxf(mrun[r], m);
          float corr = exp2f(mrun[r] - mnew);
          mrun[r] = mnew;
          lrun[r] *= corr;
#pragma unroll
          for (int fd = 0; fd < 8; fd++) oacc[fd][r] *= corr;
        }
      }
#pragma unroll
      for (int r = 0; r < 4; r++) {
#pragma unroll
        for (int fn = 0; fn < 4; fn++) {
          float pv = exp2f(p[fn][r] - mrun[r]);
          p[fn][r] = pv;
          lrun[r] += pv;
        }
      }

      // write P (bf16) to per-wave LDS, swizzled
#pragma unroll
      for (int fn = 0; fn < 4; fn++)
#pragma unroll
        for (int r = 0; r < 4; r++) {
          int qr = gl * 4 + r;
          int kc = fn * 16 + lo;
          Ps[wid][(qr * 8 + (((kc >> 3) ^ (qr & 7)))) * 8 + (kc & 7)] = f2bf(p[fn][r]);
        }

      // O += P V  (16 MFMAs)
#pragma unroll
      for (int ks2 = 0; ks2 < 2; ks2++) {
        bvec8 pf = *(const bvec8*)&Ps[wid][(lo * 8 + ((ks2 * 4 + gl) ^ (lo & 7))) * 8];
#pragma unroll
        for (int fd = 0; fd < 8; fd++) {
          bvec8 vf = *(const bvec8*)&Vs[cur][((ks2 * 4 + gl) * 128 + fd * 16 + lo) * 8];
          oacc[fd] = mfma16(pf, vf, oacc[fd]);
        }
      }

      // drain next-tile loads (issued before compute -> latency hidden), flip
      asm volatile("s_waitcnt vmcnt(0)" ::: "memory");
      __builtin_amdgcn_sched_barrier(0);
      __builtin_amdgcn_s_barrier();
      __builtin_amdgcn_sched_barrier(0);
    }

    // epilogue: reduce lrun partials, O / l -> yb [B][T][C]
#pragma unroll
    for (int r = 0; r < 4; r++) {
      float l = lrun[r];
#pragma unroll
      for (int dlt = 1; dlt < 16; dlt <<= 1) l += __shfl_xor(l, dlt);
      int qrow = q0w + gl * 4 + r;
      float inv = 1.f / l;
#pragma unroll
      for (int fd = 0; fd < 8; fd++) {
        int d = fd * 16 + lo;
        yb[((size_t)b * TT + qrow) * CC + h * DD + d] = f2bf(oacc[fd][r] * inv);
      }
    }
  }
}

extern "C" void kernel_launch(void* const* d_in, const int* in_sizes, int n_in,
                              void* d_out, int out_size, void* d_ws, size_t ws_size,
                              hipStream_t stream) {
  const float* x      = (const float*)d_in[0];
  const float* w_attn = (const float*)d_in[1];
  const float* b_attn = (const float*)d_in[2];
  const float* w_proj = (const float*)d_in[3];
  const float* b_proj = (const float*)d_in[4];
  float* out = (float*)d_out;

  char* ws = (char*)d_ws;
  unsigned short* xb    = (unsigned short*)(ws);                         // 32 MB
  unsigned short* wab_t = (unsigned short*)(ws + 33554432);              // 24 MB
  unsigned short* wpb_t = (unsigned short*)(ws + 58720256);              // 8 MB
  unsigned short* qkws  = (unsigned short*)(ws + 67108864);              // 64 MB
  unsigned short* vtws  = (unsigned short*)(ws + 134217728);             // 32 MB
  unsigned short* ybws  = (unsigned short*)(ws + 167772160);             // 32 MB

  hipLaunchKernelGGL(k_cvt, dim3(16384), dim3(256), 0, stream, x, xb, 4194304);
  hipLaunchKernelGGL(k_transpose, dim3(96, 32), dim3(256), 0, stream, w_attn, wab_t, 2048, 6144);
  hipLaunchKernelGGL(k_transpose, dim3(32, 32), dim3(256), 0, stream, w_proj, wpb_t, 2048, 2048);
  hipLaunchKernelGGL((k_gemm8<0>), dim3(24, 32), dim3(512), 0, stream,
                     xb, wab_t, b_attn, qkws, vtws, (float*)nullptr);
  hipLaunchKernelGGL(k_attn, dim3(1024), dim3(256), 0, stream, qkws, vtws, ybws);
  hipLaunchKernelGGL((k_gemm8<1>), dim3(8, 32), dim3(512), 0, stream,
                     ybws, wpb_t, b_proj, (unsigned short*)nullptr, (unsigned short*)nullptr, out);
}

// Round 5
// 448.431 us; speedup vs baseline: 1.7256x; 1.0712x over previous
//
#include <hip/hip_runtime.h>
#include <hip/hip_bf16.h>

#define NB 4
#define TT 2048
#define CC 2048
#define HH 16
#define DD 128

typedef short bvec8 __attribute__((ext_vector_type(8)));
typedef float fvec4 __attribute__((ext_vector_type(4)));

__device__ __forceinline__ void gload16(const void* g, void* l) {
  __builtin_amdgcn_global_load_lds(
      (__attribute__((address_space(1))) void*)g,
      (__attribute__((address_space(3))) void*)l, 16, 0, 0);
}

__device__ __forceinline__ unsigned short f2bf(float f) {
  union { float f; unsigned int u; } x; x.f = f;
  unsigned int u = x.u;
  return (unsigned short)((u + 0x7FFFu + ((u >> 16) & 1u)) >> 16);
}

__device__ __forceinline__ fvec4 mfma16(bvec8 a, bvec8 b, fvec4 c) {
  return __builtin_amdgcn_mfma_f32_16x16x32_bf16(a, b, c, 0, 0, 0);
}

// scale * log2(e), folded into K at the QKV epilogue
#define KSC (0.08838834764831845f * 1.4426950408889634f)

// ---------------- convert fp32 -> bf16 (vectorized) ----------------
__global__ __launch_bounds__(256) void k_cvt(const float* __restrict__ in,
                                             unsigned short* __restrict__ out, int n4) {
  int i = blockIdx.x * 256 + threadIdx.x;
  if (i >= n4) return;
  float4 v = ((const float4*)in)[i];
  ushort4 o;
  o.x = f2bf(v.x); o.y = f2bf(v.y); o.z = f2bf(v.z); o.w = f2bf(v.w);
  ((ushort4*)out)[i] = o;
}

// ---------------- transpose fp32 [R][Cn] -> bf16 [Cn][R] ----------------
__global__ __launch_bounds__(256) void k_transpose(const float* __restrict__ in,
                                                   unsigned short* __restrict__ out,
                                                   int R, int Cn) {
  __shared__ unsigned short tile[64][65];
  int tC = blockIdx.x * 64, tR = blockIdx.y * 64;
  int t = threadIdx.x;
  for (int i = 0; i < 16; i++) {
    int idx = t + i * 256; int r = idx >> 6, c = idx & 63;
    tile[r][c] = f2bf(in[(size_t)(tR + r) * Cn + tC + c]);
  }
  __syncthreads();
  for (int i = 0; i < 16; i++) {
    int idx = t + i * 256; int r = idx >> 6, c = idx & 63;
    out[(size_t)(tC + r) * R + tR + c] = tile[c][r];
  }
}

// ============ 256x256 GEMM, BK=64, 8 waves, issue-all-reads + 2 barriers/tile ============
template <int EPI>
__global__ __launch_bounds__(512, 2) void k_gemm8(
    const unsigned short* __restrict__ A,
    const unsigned short* __restrict__ Bt,
    const float* __restrict__ bias,
    unsigned short* __restrict__ qk,   // EPI=0
    unsigned short* __restrict__ vt,   // EPI=0
    float* __restrict__ out) {         // EPI=1
  const int K = CC;
  const int nt = K / 64;               // 32 K-tiles
  __shared__ unsigned short sm[2][32768];

  int tid = threadIdx.x;
  int wid = tid >> 6, ln = tid & 63, gl = ln >> 4, lo = ln & 15;
  int wr = wid >> 2, wc = wid & 3;     // 2 (M) x 4 (N) waves

  unsigned nx = gridDim.x;
  unsigned orig = blockIdx.y * nx + blockIdx.x;
  unsigned cpx = (nx * gridDim.y) >> 3;
  unsigned wg = (orig & 7) * cpx + (orig >> 3);
  int m0 = (int)(wg / nx) * 256, n0 = (int)(wg % nx) * 256;

  auto stageA = [&](int buf, int half, int kt) {
#pragma unroll
    for (int j = 0; j < 2; j++) {
      int c = j * 512 + tid;
      int r = c >> 3;
      int kc = (c & 7) ^ (r & 7);
      gload16(A + (size_t)(m0 + half * 128 + r) * K + kt * 64 + kc * 8,
              &sm[buf][(size_t)(half * 1024 + c) * 8]);
    }
  };
  auto stageB = [&](int buf, int half, int kt) {
#pragma unroll
    for (int j = 0; j < 2; j++) {
      int c = j * 512 + tid;
      int r = c >> 3;
      int kc = (c & 7) ^ (r & 7);
      gload16(Bt + (size_t)(n0 + half * 128 + r) * K + kt * 64 + kc * 8,
              &sm[buf][16384 + (size_t)(half * 1024 + c) * 8]);
    }
  };

#define AFRAG(buf, mi, ks) \
  (*(const bvec8*)&sm[buf][(((wr * 128 + (mi) * 16 + lo) * 8) + ((((ks) * 4 + gl)) ^ (lo & 7))) * 8])
#define BFRAG(buf, nj, ks) \
  (*(const bvec8*)&sm[buf][16384 + (((wc * 64 + (nj) * 16 + lo) * 8) + ((((ks) * 4 + gl)) ^ (lo & 7))) * 8])

  fvec4 acc[8][4];
  fvec4 zero = {0.f, 0.f, 0.f, 0.f};
#pragma unroll
  for (int i = 0; i < 8; i++)
#pragma unroll
    for (int j = 0; j < 4; j++) acc[i][j] = zero;

  // prologue: tile0 A+B, tile1 A (12 loads; iter-0 vmcnt(4) drains first 8)
  stageA(0, 0, 0); stageA(0, 1, 0); stageB(0, 0, 0); stageB(0, 1, 0);
  stageA(1, 0, 1); stageA(1, 1, 1);

  for (int t = 0; t < nt; t++) {
    int cur = t & 1;
    bvec8 a0[4], a1[4], a2[4], a3[4], b0[4], b1[4];

    // --- tile start: buf[cur] fully landed when only the newest 4 loads remain
    if (t + 1 < nt) {
      asm volatile("s_waitcnt vmcnt(4)" ::: "memory");
    } else {
      asm volatile("s_waitcnt vmcnt(0)" ::: "memory");
    }
    __builtin_amdgcn_sched_barrier(0);
    __builtin_amdgcn_s_barrier();
    __builtin_amdgcn_sched_barrier(0);

    // issue the bulk of the tile's LDS reads + next-tile B staging up front
#pragma unroll
    for (int mi = 0; mi < 4; mi++) a0[mi] = AFRAG(cur, mi, 0);
#pragma unroll
    for (int nj = 0; nj < 4; nj++) b0[nj] = BFRAG(cur, nj, 0);
#pragma unroll
    for (int mi = 0; mi < 4; mi++) a1[mi] = AFRAG(cur, mi + 4, 0);
#pragma unroll
    for (int mi = 0; mi < 4; mi++) a2[mi] = AFRAG(cur, mi, 1);
#pragma unroll
    for (int nj = 0; nj < 4; nj++) b1[nj] = BFRAG(cur, nj, 1);
    if (t + 1 < nt) { stageB(cur ^ 1, 0, t + 1); stageB(cur ^ 1, 1, t + 1); }
    __builtin_amdgcn_sched_barrier(0);

    // q1: a0 x b0  (compiler inserts counted lgkm waits per dependency)
    __builtin_amdgcn_s_setprio(1);
#pragma unroll
    for (int mi = 0; mi < 4; mi++)
#pragma unroll
      for (int nj = 0; nj < 4; nj++) acc[mi][nj] = mfma16(a0[mi], b0[nj], acc[mi][nj]);
    __builtin_amdgcn_s_setprio(0);

    // late-issue the last A subtile (keeps peak register pressure down)
#pragma unroll
    for (int mi = 0; mi < 4; mi++) a3[mi] = AFRAG(cur, mi + 4, 1);
    __builtin_amdgcn_sched_barrier(0);

    // q2: a1 x b0
    __builtin_amdgcn_s_setprio(1);
#pragma unroll
    for (int mi = 0; mi < 4; mi++)
#pragma unroll
      for (int nj = 0; nj < 4; nj++) acc[mi + 4][nj] = mfma16(a1[mi], b0[nj], acc[mi + 4][nj]);
    __builtin_amdgcn_s_setprio(0);

    // q3: a2 x b1
    __builtin_amdgcn_s_setprio(1);
#pragma unroll
    for (int mi = 0; mi < 4; mi++)
#pragma unroll
      for (int nj = 0; nj < 4; nj++) acc[mi][nj] = mfma16(a2[mi], b1[nj], acc[mi][nj]);
    __builtin_amdgcn_s_setprio(0);

    // all our LDS reads of buf[cur] done -> cross-wave barrier -> safe to restage A
    asm volatile("s_waitcnt lgkmcnt(0)" ::: "memory");
    __builtin_amdgcn_sched_barrier(0);
    __builtin_amdgcn_s_barrier();
    if (t + 2 < nt) { stageA(cur, 0, t + 2); stageA(cur, 1, t + 2); }

    // q4: a3 x b1
    __builtin_amdgcn_s_setprio(1);
#pragma unroll
    for (int mi = 0; mi < 4; mi++)
#pragma unroll
      for (int nj = 0; nj < 4; nj++) acc[mi + 4][nj] = mfma16(a3[mi], b1[nj], acc[mi + 4][nj]);
    __builtin_amdgcn_s_setprio(0);
  }

  // ---------------- epilogue ----------------
  if (EPI == 0) {
#pragma unroll
    for (int nj = 0; nj < 4; nj++) {
      int n = n0 + wc * 64 + nj * 16 + lo;
      float bn = bias[n];
      int s = n >> 11, hh = (n >> 7) & 15, d = n & 127;
      float mulv = (s == 1) ? KSC : 1.0f;
#pragma unroll
      for (int mi = 0; mi < 8; mi++) {
        int mb = m0 + wr * 128 + mi * 16 + gl * 4;
        int b = mb >> 11, t0 = mb & 2047;
        if (s < 2) {
          size_t base = ((((size_t)s * NB + b) * HH + hh) * TT) * DD;
#pragma unroll
          for (int r = 0; r < 4; r++)
            qk[base + (size_t)(t0 + r) * DD + d] = f2bf((acc[mi][nj][r] + bn) * mulv);
        } else {
          // vt[b][h][t/8][d][8]
          size_t base = ((((size_t)b * HH + hh) * (TT / 8) + (t0 >> 3)) * DD + d) * 8 + (t0 & 7);
          ushort4 o;
          o.x = f2bf(acc[mi][nj][0] + bn);
          o.y = f2bf(acc[mi][nj][1] + bn);
          o.z = f2bf(acc[mi][nj][2] + bn);
          o.w = f2bf(acc[mi][nj][3] + bn);
          *(ushort4*)&vt[base] = o;
        }
      }
    }
  } else {
#pragma unroll
    for (int nj = 0; nj < 4; nj++) {
      int n = n0 + wc * 64 + nj * 16 + lo;
      float bn = bias[n];
#pragma unroll
      for (int mi = 0; mi < 8; mi++) {
        int m = m0 + wr * 128 + mi * 16 + gl * 4;
#pragma unroll
        for (int r = 0; r < 4; r++) out[(size_t)(m + r) * CC + n] = acc[mi][nj][r] + bn;
      }
    }
  }
#undef AFRAG
#undef BFRAG
}

// ---------------- flash attention: 128 q-rows/block, 32 q-rows/wave, dbuf pipelined ----------------
__global__ __launch_bounds__(256, 2) void k_attn(
    const unsigned short* __restrict__ qk,   // [2][B][H][T][D], K pre-scaled
    const unsigned short* __restrict__ vt,   // [B][H][T/8][D][8]
    unsigned short* __restrict__ yb) {       // [B][T][C]
  __shared__ unsigned short Ks[2][8192];     // [kk][d] chunks, XOR-swizzled
  __shared__ unsigned short Vs[2][8192];     // [ck][d] chunks, linear
  __shared__ unsigned short Ps[4][2048];     // per-wave P: [2 mf][16][64], chunk-swizzled
  int tid = threadIdx.x, wid = tid >> 6, ln = tid & 63;
  int gl = ln >> 4, lo = ln & 15;
  int qp = blockIdx.x & 7;                   // pair index 0..7 (128-row q-tiles)
  int bh = blockIdx.x >> 3;
  int b = bh >> 4, h = bh & 15;
  const unsigned short* Q  = qk + (((size_t)b * HH + h) * TT) * DD;
  const unsigned short* Kg = qk + ((((size_t)NB + b) * HH + h) * TT) * DD;
  const unsigned short* Vg = vt + (((size_t)b * HH + h) * (TT / 8)) * DD * 8;
  fvec4 zero = {0.f, 0.f, 0.f, 0.f};

  auto stage = [&](int buf, int it) {
    int k0 = it * 64;
#pragma unroll
    for (int j = 0; j < 4; j++) {
      int c = j * 256 + tid;
      int r = c >> 4, cc = c & 15;
      gload16(Kg + (size_t)(k0 + r) * DD + ((cc ^ (r & 7)) * 8), &Ks[buf][(j * 256 + wid * 64) * 8]);
    }
#pragma unroll
    for (int j = 0; j < 4; j++) {
      int c = j * 256 + tid;
      int cc = c >> 7, d = c & 127;
      gload16(Vg + ((size_t)(k0 / 8 + cc) * DD + d) * 8, &Vs[buf][(j * 256 + wid * 64) * 8]);
    }
  };

  // per-16-row-group softmax + P write (mf selected by q0m/psoff)
  auto smax = [&](fvec4 (&sa)[4], float (&mr)[4], float (&lr)[4], fvec4 (&oa)[8],
                  int q0m, int k0, bool domask, int psoff) {
    float p[4][4], mxl[4];
#pragma unroll
    for (int r = 0; r < 4; r++) {
      int qrow = q0m + gl * 4 + r;
      float m = -1e30f;
      if (domask) {
#pragma unroll
        for (int fn = 0; fn < 4; fn++) {
          int kkg = k0 + fn * 16 + lo;
          float v = (kkg <= qrow) ? sa[fn][r] : -1e30f;
          p[fn][r] = v; m = fmaxf(m, v);
        }
      } else {
#pragma unroll
        for (int fn = 0; fn < 4; fn++) {
          float v = sa[fn][r];
          p[fn][r] = v; m = fmaxf(m, v);
        }
      }
      mxl[r] = m;
    }
    bool c = (mxl[0] > mr[0] + 8.f) || (mxl[1] > mr[1] + 8.f) ||
             (mxl[2] > mr[2] + 8.f) || (mxl[3] > mr[3] + 8.f);
    if (__any(c)) {
#pragma unroll
      for (int r = 0; r < 4; r++) {
        float m = mxl[r];
#pragma unroll
        for (int dlt = 1; dlt < 16; dlt <<= 1) m = fmaxf(m, __shfl_xor(m, dlt));
        float mnew = fmaxf(mr[r], m);
        float corr = exp2f(mr[r] - mnew);
        mr[r] = mnew; lr[r] *= corr;
#pragma unroll
        for (int fd = 0; fd < 8; fd++) oa[fd][r] *= corr;
      }
    }
#pragma unroll
    for (int r = 0; r < 4; r++)
#pragma unroll
      for (int fn = 0; fn < 4; fn++) {
        float pv = exp2f(p[fn][r] - mr[r]);
        p[fn][r] = pv; lr[r] += pv;
      }
#pragma unroll
    for (int fn = 0; fn < 4; fn++)
#pragma unroll
      for (int r = 0; r < 4; r++) {
        int qr = gl * 4 + r;
        int kc = fn * 16 + lo;
        Ps[wid][psoff + (qr * 8 + ((kc >> 3) ^ (qr & 7))) * 8 + (kc & 7)] = f2bf(p[fn][r]);
      }
  };

  for (int pass = 0; pass < 2; pass++) {
    int qt = pass ? (15 - qp) : qp;          // combined work = 34 tiles, all blocks equal
    int q0w = qt * 128 + wid * 32;

    bvec8 qf0[4], qf1[4];
#pragma unroll
    for (int ks = 0; ks < 4; ks++) {
      qf0[ks] = *(const bvec8*)(Q + (size_t)(q0w + lo) * DD + ks * 32 + gl * 8);
      qf1[ks] = *(const bvec8*)(Q + (size_t)(q0w + 16 + lo) * DD + ks * 32 + gl * 8);
    }

    fvec4 oacc0[8], oacc1[8];
#pragma unroll
    for (int i = 0; i < 8; i++) { oacc0[i] = zero; oacc1[i] = zero; }
    float mr0[4] = {-1e30f, -1e30f, -1e30f, -1e30f};
    float mr1[4] = {-1e30f, -1e30f, -1e30f, -1e30f};
    float lr0[4] = {0.f, 0.f, 0.f, 0.f};
    float lr1[4] = {0.f, 0.f, 0.f, 0.f};

    int ntiles = 2 * qt + 2;
    stage(0, 0);
    asm volatile("s_waitcnt vmcnt(0)" ::: "memory");
    __builtin_amdgcn_sched_barrier(0);
    __builtin_amdgcn_s_barrier();
    __builtin_amdgcn_sched_barrier(0);

    for (int it = 0; it < ntiles; it++) {
      int cur = it & 1;
      int k0 = it * 64;
      if (it + 1 < ntiles) stage(cur ^ 1, it + 1);

      // S = Q K^T: 32 MFMAs sharing 16 K-frag reads
      fvec4 sa0[4], sa1[4];
#pragma unroll
      for (int fn = 0; fn < 4; fn++) {
        fvec4 s0 = zero, s1 = zero;
#pragma unroll
        for (int ks = 0; ks < 4; ks++) {
          int r = fn * 16 + lo;
          int cd = ks * 4 + gl;
          bvec8 kf = *(const bvec8*)&Ks[cur][(r * 16 + (cd ^ (r & 7))) * 8];
          s0 = mfma16(qf0[ks], kf, s0);
          s1 = mfma16(qf1[ks], kf, s1);
        }
        sa0[fn] = s0; sa1[fn] = s1;
      }

      smax(sa0, mr0, lr0, oacc0, q0w,      k0, (k0 + 63) > q0w,        0);
      smax(sa1, mr1, lr1, oacc1, q0w + 16, k0, (k0 + 63) > (q0w + 16), 1024);

      // O += P V: 32 MFMAs sharing 16 V-frag reads
#pragma unroll
      for (int ks2 = 0; ks2 < 2; ks2++) {
        bvec8 pf0 = *(const bvec8*)&Ps[wid][(lo * 8 + ((ks2 * 4 + gl) ^ (lo & 7))) * 8];
        bvec8 pf1 = *(const bvec8*)&Ps[wid][1024 + (lo * 8 + ((ks2 * 4 + gl) ^ (lo & 7))) * 8];
#pragma unroll
        for (int fd = 0; fd < 8; fd++) {
          bvec8 vf = *(const bvec8*)&Vs[cur][((ks2 * 4 + gl) * 128 + fd * 16 + lo) * 8];
          oacc0[fd] = mfma16(pf0, vf, oacc0[fd]);
          oacc1[fd] = mfma16(pf1, vf, oacc1[fd]);
        }
      }

      asm volatile("s_waitcnt vmcnt(0)" ::: "memory");
      __builtin_amdgcn_sched_barrier(0);
      __builtin_amdgcn_s_barrier();
      __builtin_amdgcn_sched_barrier(0);
    }

    // epilogue
#pragma unroll
    for (int r = 0; r < 4; r++) {
      float l0 = lr0[r], l1 = lr1[r];
#pragma unroll
      for (int dlt = 1; dlt < 16; dlt <<= 1) {
        l0 += __shfl_xor(l0, dlt);
        l1 += __shfl_xor(l1, dlt);
      }
      int qrow0 = q0w + gl * 4 + r;
      int qrow1 = q0w + 16 + gl * 4 + r;
      float inv0 = 1.f / l0, inv1 = 1.f / l1;
#pragma unroll
      for (int fd = 0; fd < 8; fd++) {
        int d = fd * 16 + lo;
        yb[((size_t)b * TT + qrow0) * CC + h * DD + d] = f2bf(oacc0[fd][r] * inv0);
        yb[((size_t)b * TT + qrow1) * CC + h * DD + d] = f2bf(oacc1[fd][r] * inv1);
      }
    }
  }
}

extern "C" void kernel_launch(void* const* d_in, const int* in_sizes, int n_in,
                              void* d_out, int out_size, void* d_ws, size_t ws_size,
                              hipStream_t stream) {
  const float* x      = (const float*)d_in[0];
  const float* w_attn = (const float*)d_in[1];
  const float* b_attn = (const float*)d_in[2];
  const float* w_proj = (const float*)d_in[3];
  const float* b_proj = (const float*)d_in[4];
  float* out = (float*)d_out;

  char* ws = (char*)d_ws;
  unsigned short* xb    = (unsigned short*)(ws);                         // 32 MB
  unsigned short* wab_t = (unsigned short*)(ws + 33554432);              // 24 MB
  unsigned short* wpb_t = (unsigned short*)(ws + 58720256);              // 8 MB
  unsigned short* qkws  = (unsigned short*)(ws + 67108864);              // 64 MB
  unsigned short* vtws  = (unsigned short*)(ws + 134217728);             // 32 MB
  unsigned short* ybws  = (unsigned short*)(ws + 167772160);             // 32 MB

  hipLaunchKernelGGL(k_cvt, dim3(16384), dim3(256), 0, stream, x, xb, 4194304);
  hipLaunchKernelGGL(k_transpose, dim3(96, 32), dim3(256), 0, stream, w_attn, wab_t, 2048, 6144);
  hipLaunchKernelGGL(k_transpose, dim3(32, 32), dim3(256), 0, stream, w_proj, wpb_t, 2048, 2048);
  hipLaunchKernelGGL((k_gemm8<0>), dim3(24, 32), dim3(512), 0, stream,
                     xb, wab_t, b_attn, qkws, vtws, (float*)nullptr);
  hipLaunchKernelGGL(k_attn, dim3(512), dim3(256), 0, stream, qkws, vtws, ybws);
  hipLaunchKernelGGL((k_gemm8<1>), dim3(8, 32), dim3(512), 0, stream,
                     ybws, wpb_t, b_proj, (unsigned short*)nullptr, (unsigned short*)nullptr, out);
}

// Round 6
// 444.049 us; speedup vs baseline: 1.7427x; 1.0099x over previous
//
#include <hip/hip_runtime.h>
#include <hip/hip_bf16.h>

#define NB 4
#define TT 2048
#define CC 2048
#define HH 16
#define DD 128

typedef short bvec8 __attribute__((ext_vector_type(8)));
typedef float fvec4 __attribute__((ext_vector_type(4)));

__device__ __forceinline__ void gload16(const void* g, void* l) {
  __builtin_amdgcn_global_load_lds(
      (__attribute__((address_space(1))) void*)g,
      (__attribute__((address_space(3))) void*)l, 16, 0, 0);
}

__device__ __forceinline__ unsigned short f2bf(float f) {
  union { float f; unsigned int u; } x; x.f = f;
  unsigned int u = x.u;
  return (unsigned short)((u + 0x7FFFu + ((u >> 16) & 1u)) >> 16);
}

__device__ __forceinline__ fvec4 mfma16(bvec8 a, bvec8 b, fvec4 c) {
  return __builtin_amdgcn_mfma_f32_16x16x32_bf16(a, b, c, 0, 0, 0);
}

// scale * log2(e), folded into K at the QKV epilogue
#define KSC (0.08838834764831845f * 1.4426950408889634f)

// ---------------- convert fp32 -> bf16 (vectorized) ----------------
__global__ __launch_bounds__(256) void k_cvt(const float* __restrict__ in,
                                             unsigned short* __restrict__ out, int n4) {
  int i = blockIdx.x * 256 + threadIdx.x;
  if (i >= n4) return;
  float4 v = ((const float4*)in)[i];
  ushort4 o;
  o.x = f2bf(v.x); o.y = f2bf(v.y); o.z = f2bf(v.z); o.w = f2bf(v.w);
  ((ushort4*)out)[i] = o;
}

// ---------------- transpose fp32 [R][Cn] -> bf16 [Cn][R] ----------------
__global__ __launch_bounds__(256) void k_transpose(const float* __restrict__ in,
                                                   unsigned short* __restrict__ out,
                                                   int R, int Cn) {
  __shared__ unsigned short tile[64][65];
  int tC = blockIdx.x * 64, tR = blockIdx.y * 64;
  int t = threadIdx.x;
  for (int i = 0; i < 16; i++) {
    int idx = t + i * 256; int r = idx >> 6, c = idx & 63;
    tile[r][c] = f2bf(in[(size_t)(tR + r) * Cn + tC + c]);
  }
  __syncthreads();
  for (int i = 0; i < 16; i++) {
    int idx = t + i * 256; int r = idx >> 6, c = idx & 63;
    out[(size_t)(tC + r) * R + tR + c] = tile[c][r];
  }
}

// ============ 256x256 GEMM, BK=64, 8 waves, distance-2 staging both operands ============
template <int EPI>
__global__ __launch_bounds__(512, 2) void k_gemm8(
    const unsigned short* __restrict__ A,
    const unsigned short* __restrict__ Bt,
    const float* __restrict__ bias,
    unsigned short* __restrict__ qk,   // EPI=0
    unsigned short* __restrict__ vt,   // EPI=0
    float* __restrict__ out) {         // EPI=1
  const int K = CC;
  const int nt = K / 64;               // 32 K-tiles
  __shared__ unsigned short sm[2][32768];

  int tid = threadIdx.x;
  int wid = tid >> 6, ln = tid & 63, gl = ln >> 4, lo = ln & 15;
  int wr = wid >> 2, wc = wid & 3;     // 2 (M) x 4 (N) waves

  unsigned nx = gridDim.x;
  unsigned orig = blockIdx.y * nx + blockIdx.x;
  unsigned cpx = (nx * gridDim.y) >> 3;
  unsigned wg = (orig & 7) * cpx + (orig >> 3);
  int m0 = (int)(wg / nx) * 256, n0 = (int)(wg % nx) * 256;

  auto stageA = [&](int buf, int half, int kt) {
#pragma unroll
    for (int j = 0; j < 2; j++) {
      int c = j * 512 + tid;
      int r = c >> 3;
      int kc = (c & 7) ^ (r & 7);
      gload16(A + (size_t)(m0 + half * 128 + r) * K + kt * 64 + kc * 8,
              &sm[buf][(size_t)(half * 1024 + c) * 8]);
    }
  };
  auto stageB = [&](int buf, int half, int kt) {
#pragma unroll
    for (int j = 0; j < 2; j++) {
      int c = j * 512 + tid;
      int r = c >> 3;
      int kc = (c & 7) ^ (r & 7);
      gload16(Bt + (size_t)(n0 + half * 128 + r) * K + kt * 64 + kc * 8,
              &sm[buf][16384 + (size_t)(half * 1024 + c) * 8]);
    }
  };

#define AFRAG(buf, mi, ks) \
  (*(const bvec8*)&sm[buf][(((wr * 128 + (mi) * 16 + lo) * 8) + ((((ks) * 4 + gl)) ^ (lo & 7))) * 8])
#define BFRAG(buf, nj, ks) \
  (*(const bvec8*)&sm[buf][16384 + (((wc * 64 + (nj) * 16 + lo) * 8) + ((((ks) * 4 + gl)) ^ (lo & 7))) * 8])

  fvec4 acc[8][4];
  fvec4 zero = {0.f, 0.f, 0.f, 0.f};
#pragma unroll
  for (int i = 0; i < 8; i++)
#pragma unroll
    for (int j = 0; j < 4; j++) acc[i][j] = zero;

  // prologue: tile0 batch (8 loads) then tile1 batch (8 loads) — FIFO order matters
  stageA(0, 0, 0); stageA(0, 1, 0); stageB(0, 0, 0); stageB(0, 1, 0);
  stageA(1, 0, 1); stageA(1, 1, 1); stageB(1, 0, 1); stageB(1, 1, 1);

  for (int t = 0; t < nt; t++) {
    int cur = t & 1;
    bvec8 a0[4], a1[4], a2[4], a3[4], b0[4], b1[4];

    // --- tile start: tile t's 8 loads landed when only the newest 8 (t+1's) remain
    if (t + 1 < nt) {
      asm volatile("s_waitcnt vmcnt(8)" ::: "memory");
    } else {
      asm volatile("s_waitcnt vmcnt(0)" ::: "memory");
    }
    __builtin_amdgcn_sched_barrier(0);
    __builtin_amdgcn_s_barrier();
    __builtin_amdgcn_sched_barrier(0);

    // issue the bulk of the tile's LDS reads up front
#pragma unroll
    for (int mi = 0; mi < 4; mi++) a0[mi] = AFRAG(cur, mi, 0);
#pragma unroll
    for (int nj = 0; nj < 4; nj++) b0[nj] = BFRAG(cur, nj, 0);
#pragma unroll
    for (int mi = 0; mi < 4; mi++) a1[mi] = AFRAG(cur, mi + 4, 0);
#pragma unroll
    for (int mi = 0; mi < 4; mi++) a2[mi] = AFRAG(cur, mi, 1);
#pragma unroll
    for (int nj = 0; nj < 4; nj++) b1[nj] = BFRAG(cur, nj, 1);
    __builtin_amdgcn_sched_barrier(0);

    // q1: a0 x b0  (compiler inserts counted lgkm waits per dependency)
    __builtin_amdgcn_s_setprio(1);
#pragma unroll
    for (int mi = 0; mi < 4; mi++)
#pragma unroll
      for (int nj = 0; nj < 4; nj++) acc[mi][nj] = mfma16(a0[mi], b0[nj], acc[mi][nj]);
    __builtin_amdgcn_s_setprio(0);

    // late-issue the last A subtile (keeps peak register pressure down)
#pragma unroll
    for (int mi = 0; mi < 4; mi++) a3[mi] = AFRAG(cur, mi + 4, 1);
    __builtin_amdgcn_sched_barrier(0);

    // q2: a1 x b0
    __builtin_amdgcn_s_setprio(1);
#pragma unroll
    for (int mi = 0; mi < 4; mi++)
#pragma unroll
      for (int nj = 0; nj < 4; nj++) acc[mi + 4][nj] = mfma16(a1[mi], b0[nj], acc[mi + 4][nj]);
    __builtin_amdgcn_s_setprio(0);

    // q3: a2 x b1
    __builtin_amdgcn_s_setprio(1);
#pragma unroll
    for (int mi = 0; mi < 4; mi++)
#pragma unroll
      for (int nj = 0; nj < 4; nj++) acc[mi][nj] = mfma16(a2[mi], b1[nj], acc[mi][nj]);
    __builtin_amdgcn_s_setprio(0);

    // all LDS reads of buf[cur] done (A and B) -> barrier -> restage BOTH into buf[cur] for t+2
    asm volatile("s_waitcnt lgkmcnt(0)" ::: "memory");
    __builtin_amdgcn_sched_barrier(0);
    __builtin_amdgcn_s_barrier();
    if (t + 2 < nt) {
      stageA(cur, 0, t + 2); stageA(cur, 1, t + 2);
      stageB(cur, 0, t + 2); stageB(cur, 1, t + 2);
    }

    // q4: a3 x b1
    __builtin_amdgcn_s_setprio(1);
#pragma unroll
    for (int mi = 0; mi < 4; mi++)
#pragma unroll
      for (int nj = 0; nj < 4; nj++) acc[mi + 4][nj] = mfma16(a3[mi], b1[nj], acc[mi + 4][nj]);
    __builtin_amdgcn_s_setprio(0);
  }

  // ---------------- epilogue ----------------
  if (EPI == 0) {
#pragma unroll
    for (int nj = 0; nj < 4; nj++) {
      int n = n0 + wc * 64 + nj * 16 + lo;
      float bn = bias[n];
      int s = n >> 11, hh = (n >> 7) & 15, d = n & 127;
      float mulv = (s == 1) ? KSC : 1.0f;
#pragma unroll
      for (int mi = 0; mi < 8; mi++) {
        int mb = m0 + wr * 128 + mi * 16 + gl * 4;
        int b = mb >> 11, t0 = mb & 2047;
        if (s < 2) {
          size_t base = ((((size_t)s * NB + b) * HH + hh) * TT) * DD;
#pragma unroll
          for (int r = 0; r < 4; r++)
            qk[base + (size_t)(t0 + r) * DD + d] = f2bf((acc[mi][nj][r] + bn) * mulv);
        } else {
          // vt[b][h][t/8][d][8]
          size_t base = ((((size_t)b * HH + hh) * (TT / 8) + (t0 >> 3)) * DD + d) * 8 + (t0 & 7);
          ushort4 o;
          o.x = f2bf(acc[mi][nj][0] + bn);
          o.y = f2bf(acc[mi][nj][1] + bn);
          o.z = f2bf(acc[mi][nj][2] + bn);
          o.w = f2bf(acc[mi][nj][3] + bn);
          *(ushort4*)&vt[base] = o;
        }
      }
    }
  } else {
#pragma unroll
    for (int nj = 0; nj < 4; nj++) {
      int n = n0 + wc * 64 + nj * 16 + lo;
      float bn = bias[n];
#pragma unroll
      for (int mi = 0; mi < 8; mi++) {
        int m = m0 + wr * 128 + mi * 16 + gl * 4;
#pragma unroll
        for (int r = 0; r < 4; r++) out[(size_t)(m + r) * CC + n] = acc[mi][nj][r] + bn;
      }
    }
  }
#undef AFRAG
#undef BFRAG
}

// ---------------- flash attention: 128 q-rows/block, 32 q-rows/wave, split K/V waits ----------------
__global__ __launch_bounds__(256, 2) void k_attn(
    const unsigned short* __restrict__ qk,   // [2][B][H][T][D], K pre-scaled
    const unsigned short* __restrict__ vt,   // [B][H][T/8][D][8]
    unsigned short* __restrict__ yb) {       // [B][T][C]
  __shared__ unsigned short Ks[2][8192];     // [kk][d] chunks, XOR-swizzled
  __shared__ unsigned short Vs[2][8192];     // [ck][d] chunks, linear
  __shared__ unsigned short Ps[4][2048];     // per-wave P: [2 mf][16][64], chunk-swizzled
  int tid = threadIdx.x, wid = tid >> 6, ln = tid & 63;
  int gl = ln >> 4, lo = ln & 15;
  int qp = blockIdx.x & 7;                   // pair index 0..7 (128-row q-tiles)
  int bh = blockIdx.x >> 3;
  int b = bh >> 4, h = bh & 15;
  const unsigned short* Q  = qk + (((size_t)b * HH + h) * TT) * DD;
  const unsigned short* Kg = qk + ((((size_t)NB + b) * HH + h) * TT) * DD;
  const unsigned short* Vg = vt + (((size_t)b * HH + h) * (TT / 8)) * DD * 8;
  fvec4 zero = {0.f, 0.f, 0.f, 0.f};

  // K first (8 loads), then V (8 loads) — FIFO split-wait depends on this order
  auto stageK = [&](int buf, int it) {
    int k0 = it * 64;
#pragma unroll
    for (int j = 0; j < 4; j++) {
      int c = j * 256 + tid;
      int r = c >> 4, cc = c & 15;
      gload16(Kg + (size_t)(k0 + r) * DD + ((cc ^ (r & 7)) * 8), &Ks[buf][(j * 256 + wid * 64) * 8]);
    }
  };
  auto stageV = [&](int buf, int it) {
    int k0 = it * 64;
#pragma unroll
    for (int j = 0; j < 4; j++) {
      int c = j * 256 + tid;
      int cc = c >> 7, d = c & 127;
      gload16(Vg + ((size_t)(k0 / 8 + cc) * DD + d) * 8, &Vs[buf][(j * 256 + wid * 64) * 8]);
    }
  };

  // per-16-row-group softmax + P write (mf selected by q0m/psoff)
  auto smax = [&](fvec4 (&sa)[4], float (&mr)[4], float (&lr)[4], fvec4 (&oa)[8],
                  int q0m, int k0, bool domask, int psoff) {
    float p[4][4], mxl[4];
#pragma unroll
    for (int r = 0; r < 4; r++) {
      int qrow = q0m + gl * 4 + r;
      float m = -1e30f;
      if (domask) {
#pragma unroll
        for (int fn = 0; fn < 4; fn++) {
          int kkg = k0 + fn * 16 + lo;
          float v = (kkg <= qrow) ? sa[fn][r] : -1e30f;
          p[fn][r] = v; m = fmaxf(m, v);
        }
      } else {
#pragma unroll
        for (int fn = 0; fn < 4; fn++) {
          float v = sa[fn][r];
          p[fn][r] = v; m = fmaxf(m, v);
        }
      }
      mxl[r] = m;
    }
    bool c = (mxl[0] > mr[0] + 8.f) || (mxl[1] > mr[1] + 8.f) ||
             (mxl[2] > mr[2] + 8.f) || (mxl[3] > mr[3] + 8.f);
    if (__any(c)) {
#pragma unroll
      for (int r = 0; r < 4; r++) {
        float m = mxl[r];
#pragma unroll
        for (int dlt = 1; dlt < 16; dlt <<= 1) m = fmaxf(m, __shfl_xor(m, dlt));
        float mnew = fmaxf(mr[r], m);
        float corr = exp2f(mr[r] - mnew);
        mr[r] = mnew; lr[r] *= corr;
#pragma unroll
        for (int fd = 0; fd < 8; fd++) oa[fd][r] *= corr;
      }
    }
#pragma unroll
    for (int r = 0; r < 4; r++)
#pragma unroll
      for (int fn = 0; fn < 4; fn++) {
        float pv = exp2f(p[fn][r] - mr[r]);
        p[fn][r] = pv; lr[r] += pv;
      }
#pragma unroll
    for (int fn = 0; fn < 4; fn++)
#pragma unroll
      for (int r = 0; r < 4; r++) {
        int qr = gl * 4 + r;
        int kc = fn * 16 + lo;
        Ps[wid][psoff + (qr * 8 + ((kc >> 3) ^ (qr & 7))) * 8 + (kc & 7)] = f2bf(p[fn][r]);
      }
  };

  for (int pass = 0; pass < 2; pass++) {
    int qt = pass ? (15 - qp) : qp;          // combined work = 34 tiles, all blocks equal
    int q0w = qt * 128 + wid * 32;

    bvec8 qf0[4], qf1[4];
#pragma unroll
    for (int ks = 0; ks < 4; ks++) {
      qf0[ks] = *(const bvec8*)(Q + (size_t)(q0w + lo) * DD + ks * 32 + gl * 8);
      qf1[ks] = *(const bvec8*)(Q + (size_t)(q0w + 16 + lo) * DD + ks * 32 + gl * 8);
    }

    fvec4 oacc0[8], oacc1[8];
#pragma unroll
    for (int i = 0; i < 8; i++) { oacc0[i] = zero; oacc1[i] = zero; }
    float mr0[4] = {-1e30f, -1e30f, -1e30f, -1e30f};
    float mr1[4] = {-1e30f, -1e30f, -1e30f, -1e30f};
    float lr0[4] = {0.f, 0.f, 0.f, 0.f};
    float lr1[4] = {0.f, 0.f, 0.f, 0.f};

    int ntiles = 2 * qt + 2;
    stageK(0, 0); stageV(0, 0);
    asm volatile("s_waitcnt vmcnt(8)" ::: "memory");  // K(0) landed; V(0) may fly
    __builtin_amdgcn_sched_barrier(0);
    __builtin_amdgcn_s_barrier();
    __builtin_amdgcn_sched_barrier(0);

    for (int it = 0; it < ntiles; it++) {
      int cur = it & 1;
      int k0 = it * 64;
      bool more = (it + 1 < ntiles);
      if (more) { stageK(cur ^ 1, it + 1); stageV(cur ^ 1, it + 1); }

      // S = Q K^T: 32 MFMAs sharing 16 K-frag reads
      fvec4 sa0[4], sa1[4];
#pragma unroll
      for (int fn = 0; fn < 4; fn++) {
        fvec4 s0 = zero, s1 = zero;
#pragma unroll
        for (int ks = 0; ks < 4; ks++) {
          int r = fn * 16 + lo;
          int cd = ks * 4 + gl;
          bvec8 kf = *(const bvec8*)&Ks[cur][(r * 16 + (cd ^ (r & 7))) * 8];
          s0 = mfma16(qf0[ks], kf, s0);
          s1 = mfma16(qf1[ks], kf, s1);
        }
        sa0[fn] = s0; sa1[fn] = s1;
      }

      smax(sa0, mr0, lr0, oacc0, q0w,      k0, (k0 + 63) > q0w,        0);
      smax(sa1, mr1, lr1, oacc1, q0w + 16, k0, (k0 + 63) > (q0w + 16), 1024);

      // pre-PV: V(cur) landed when only the 16 newer loads (next tile's K+V) remain
      if (more) {
        asm volatile("s_waitcnt vmcnt(16)" ::: "memory");
      } else {
        asm volatile("s_waitcnt vmcnt(0)" ::: "memory");
      }
      __builtin_amdgcn_sched_barrier(0);
      __builtin_amdgcn_s_barrier();
      __builtin_amdgcn_sched_barrier(0);

      // O += P V: 32 MFMAs sharing 16 V-frag reads
#pragma unroll
      for (int ks2 = 0; ks2 < 2; ks2++) {
        bvec8 pf0 = *(const bvec8*)&Ps[wid][(lo * 8 + ((ks2 * 4 + gl) ^ (lo & 7))) * 8];
        bvec8 pf1 = *(const bvec8*)&Ps[wid][1024 + (lo * 8 + ((ks2 * 4 + gl) ^ (lo & 7))) * 8];
#pragma unroll
        for (int fd = 0; fd < 8; fd++) {
          bvec8 vf = *(const bvec8*)&Vs[cur][((ks2 * 4 + gl) * 128 + fd * 16 + lo) * 8];
          oacc0[fd] = mfma16(pf0, vf, oacc0[fd]);
          oacc1[fd] = mfma16(pf1, vf, oacc1[fd]);
        }
      }

      // end-of-tile: K(it+1) landed when only the 8 newer V-loads remain
      if (more) {
        asm volatile("s_waitcnt vmcnt(8)" ::: "memory");
      } else {
        asm volatile("s_waitcnt vmcnt(0)" ::: "memory");
      }
      __builtin_amdgcn_sched_barrier(0);
      __builtin_amdgcn_s_barrier();
      __builtin_amdgcn_sched_barrier(0);
    }

    // epilogue
#pragma unroll
    for (int r = 0; r < 4; r++) {
      float l0 = lr0[r], l1 = lr1[r];
#pragma unroll
      for (int dlt = 1; dlt < 16; dlt <<= 1) {
        l0 += __shfl_xor(l0, dlt);
        l1 += __shfl_xor(l1, dlt);
      }
      int qrow0 = q0w + gl * 4 + r;
      int qrow1 = q0w + 16 + gl * 4 + r;
      float inv0 = 1.f / l0, inv1 = 1.f / l1;
#pragma unroll
      for (int fd = 0; fd < 8; fd++) {
        int d = fd * 16 + lo;
        yb[((size_t)b * TT + qrow0) * CC + h * DD + d] = f2bf(oacc0[fd][r] * inv0);
        yb[((size_t)b * TT + qrow1) * CC + h * DD + d] = f2bf(oacc1[fd][r] * inv1);
      }
    }
  }
}

extern "C" void kernel_launch(void* const* d_in, const int* in_sizes, int n_in,
                              void* d_out, int out_size, void* d_ws, size_t ws_size,
                              hipStream_t stream) {
  const float* x      = (const float*)d_in[0];
  const float* w_attn = (const float*)d_in[1];
  const float* b_attn = (const float*)d_in[2];
  const float* w_proj = (const float*)d_in[3];
  const float* b_proj = (const float*)d_in[4];
  float* out = (float*)d_out;

  char* ws = (char*)d_ws;
  unsigned short* xb    = (unsigned short*)(ws);                         // 32 MB
  unsigned short* wab_t = (unsigned short*)(ws + 33554432);              // 24 MB
  unsigned short* wpb_t = (unsigned short*)(ws + 58720256);              // 8 MB
  unsigned short* qkws  = (unsigned short*)(ws + 67108864);              // 64 MB
  unsigned short* vtws  = (unsigned short*)(ws + 134217728);             // 32 MB
  unsigned short* ybws  = (unsigned short*)(ws + 167772160);             // 32 MB

  hipLaunchKernelGGL(k_cvt, dim3(16384), dim3(256), 0, stream, x, xb, 4194304);
  hipLaunchKernelGGL(k_transpose, dim3(96, 32), dim3(256), 0, stream, w_attn, wab_t, 2048, 6144);
  hipLaunchKernelGGL(k_transpose, dim3(32, 32), dim3(256), 0, stream, w_proj, wpb_t, 2048, 2048);
  hipLaunchKernelGGL((k_gemm8<0>), dim3(24, 32), dim3(512), 0, stream,
                     xb, wab_t, b_attn, qkws, vtws, (float*)nullptr);
  hipLaunchKernelGGL(k_attn, dim3(512), dim3(256), 0, stream, qkws, vtws, ybws);
  hipLaunchKernelGGL((k_gemm8<1>), dim3(8, 32), dim3(512), 0, stream,
                     ybws, wpb_t, b_proj, (unsigned short*)nullptr, (unsigned short*)nullptr, out);
}